// Round 24
// baseline (5749.083 us; speedup 1.0000x reference)
//
#include <hip/hip_runtime.h>
#include <stdint.h>

#define LAYERS    5
#define INPUT_DIM 512
#define CODE_DIM  2048
#define BATCH     32768
#define KSP       32
#define NCAND     40

typedef __attribute__((ext_vector_type(8))) short bf16x8;
typedef __attribute__((ext_vector_type(4))) float f32x4;

__device__ __forceinline__ unsigned short f2bf(float f) {
    uint32_t u = __float_as_uint(f);
    uint32_t r = (u + 0x7fffu + ((u >> 16) & 1u)) >> 16;   // RNE
    return (unsigned short)r;
}

// za region select: rows [0,16384) -> zaA, [16384,24576) -> zaB, rest -> zaC
__device__ __forceinline__ float* za_row(float* zaA, float* zaB, float* zaC, int row) {
    return (row < 16384) ? zaA + (size_t)row * CODE_DIM
         : (row < 24576) ? zaB + (size_t)(row - 16384) * CODE_DIM
                         : zaC + (size_t)(row - 24576) * CODE_DIM;
}

#define GLOAD_LDS16(dst, src) \
    __builtin_amdgcn_global_load_lds((const __attribute__((address_space(1))) uint32_t*)(src), \
                                     (__attribute__((address_space(3))) uint32_t*)(dst), 16, 0, 0)

// ---------------------------------------------------------------------------
// src [512][2048] f32 -> dst [2048][512] f32  (bit copy; used for Dt)
__global__ __launch_bounds__(256) void transpose_512x2048_kernel(const float* __restrict__ src,
                                                                 float* __restrict__ dst)
{
    __shared__ float tile[32][33];
    const int tx = threadIdx.x;
    const int ty = threadIdx.y;
    const int cb = blockIdx.x * 32;
    const int ib = blockIdx.y * 32;
    #pragma unroll
    for (int j = 0; j < 32; j += 8)
        tile[ty + j][tx] = src[(size_t)(ib + ty + j) * CODE_DIM + cb + tx];
    __syncthreads();
    #pragma unroll
    for (int j = 0; j < 32; j += 8)
        dst[(size_t)(cb + ty + j) * INPUT_DIM + ib + tx] = tile[tx][ty + j];
}

// ---------------------------------------------------------------------------
// W [512][2048] f32 -> WT [2048][512] f32 AND WbT [2048][512] bf16 (one pass)
__global__ __launch_bounds__(256) void wt_dual_kernel(const float* __restrict__ src,
                                                      float* __restrict__ wt,
                                                      unsigned short* __restrict__ wbt)
{
    __shared__ float tile[32][33];
    const int tx = threadIdx.x;
    const int ty = threadIdx.y;
    const int cb = blockIdx.x * 32;
    const int ib = blockIdx.y * 32;
    #pragma unroll
    for (int j = 0; j < 32; j += 8)
        tile[ty + j][tx] = src[(size_t)(ib + ty + j) * CODE_DIM + cb + tx];
    __syncthreads();
    #pragma unroll
    for (int j = 0; j < 32; j += 8) {
        float v = tile[tx][ty + j];
        wt [(size_t)(cb + ty + j) * INPUT_DIM + ib + tx] = v;
        wbt[(size_t)(cb + ty + j) * INPUT_DIM + ib + tx] = f2bf(v);
    }
}

// ---------------------------------------------------------------------------
// x f32 [32768*512] -> xb bf16 (8 elems/thread)
__global__ __launch_bounds__(256) void cvt_x_kernel(const float* __restrict__ s,
                                                    unsigned short* __restrict__ d)
{
    const size_t base = ((size_t)blockIdx.x * 256 + threadIdx.x) * 8;
    float4 a = *(const float4*)&s[base];
    float4 b = *(const float4*)&s[base + 4];
    uint4 o;
    o.x = (uint32_t)f2bf(a.x) | ((uint32_t)f2bf(a.y) << 16);
    o.y = (uint32_t)f2bf(a.z) | ((uint32_t)f2bf(a.w) << 16);
    o.z = (uint32_t)f2bf(b.x) | ((uint32_t)f2bf(b.y) << 16);
    o.w = (uint32_t)f2bf(b.z) | ((uint32_t)f2bf(b.w) << 16);
    *(uint4*)&d[base] = o;
}

// ---------------------------------------------------------------------------
// SCREEN (pure bf16 MFMA xW).  Double-buffered gload-only LDS staging.
// Fragment maps validated r17.
__global__ __launch_bounds__(256) void screen_kernel(
    const unsigned short* __restrict__ xb, const unsigned short* __restrict__ WbT,
    unsigned short* __restrict__ u)
{
    __shared__ unsigned short Ash[2][128][32];   // 16 KB, gload dest (linear)
    __shared__ unsigned short Bsh[2][128][32];   // 16 KB

    const int t    = threadIdx.x;
    const int lane = t & 63;
    const int w    = t >> 6;
    const int m16  = lane & 15;
    const int g    = lane >> 4;
    const int c0   = blockIdx.x * 128;
    const int r0   = blockIdx.y * 128;

    const int srow  = lane >> 2;              // 0..15
    const int spart = (lane & 3) * 8;         // short offset within row

#define GLOAD_T(B, KT)                                                        \
    GLOAD_LDS16(&Ash[B][w * 32][0],                                           \
        xb  + (size_t)(r0 + w * 32 + srow) * INPUT_DIM + (KT) + spart);       \
    GLOAD_LDS16(&Ash[B][w * 32 + 16][0],                                      \
        xb  + (size_t)(r0 + w * 32 + 16 + srow) * INPUT_DIM + (KT) + spart);  \
    GLOAD_LDS16(&Bsh[B][w * 32][0],                                           \
        WbT + (size_t)(c0 + w * 32 + srow) * INPUT_DIM + (KT) + spart);       \
    GLOAD_LDS16(&Bsh[B][w * 32 + 16][0],                                      \
        WbT + (size_t)(c0 + w * 32 + 16 + srow) * INPUT_DIM + (KT) + spart);

#define COMPUTE_T(B)                                                          \
    {                                                                         \
        bf16x8 af0 = *(const bf16x8*)&Ash[B][w * 32 + m16][g * 8];            \
        bf16x8 af1 = *(const bf16x8*)&Ash[B][w * 32 + 16 + m16][g * 8];       \
        _Pragma("unroll")                                                     \
        for (int ns = 0; ns < 8; ++ns) {                                      \
            bf16x8 bfv = *(const bf16x8*)&Bsh[B][ns * 16 + m16][g * 8];       \
            acc[0][ns] = __builtin_amdgcn_mfma_f32_16x16x32_bf16(af0, bfv, acc[0][ns], 0, 0, 0); \
            acc[1][ns] = __builtin_amdgcn_mfma_f32_16x16x32_bf16(af1, bfv, acc[1][ns], 0, 0, 0); \
        }                                                                     \
    }

    f32x4 acc[2][8];
    #pragma unroll
    for (int mr = 0; mr < 2; ++mr)
        #pragma unroll
        for (int ns = 0; ns < 8; ++ns) acc[mr][ns] = (f32x4){0.f, 0.f, 0.f, 0.f};

    GLOAD_T(0, 0);
    __syncthreads();

    for (int kt = 0; kt < INPUT_DIM; kt += 64) {
        GLOAD_T(1, kt + 32);
        COMPUTE_T(0);
        __syncthreads();
        if (kt + 64 < INPUT_DIM) {
            GLOAD_T(0, kt + 64);
        }
        COMPUTE_T(1);
        __syncthreads();
    }

#undef GLOAD_T
#undef COMPUTE_T

    #pragma unroll
    for (int mr = 0; mr < 2; ++mr)
        #pragma unroll
        for (int ns = 0; ns < 8; ++ns)
            #pragma unroll
            for (int q = 0; q < 4; ++q) {
                const int row = r0 + w * 32 + mr * 16 + g * 4 + q;
                u[(size_t)row * CODE_DIM + c0 + ns * 16 + m16] = f2bf(acc[mr][ns][q]);
            }
}

// ---------------------------------------------------------------------------
// ZA_ADD: block-parallel exact za (contract chain: zero-init, ascending-index
// fold, f32 fmaf) for 128 rows x 256 cols per block.  Dense za only.
// Grid: blockIdx.x = row group (fast), blockIdx.y = column panel (slow) ->
// 2 MB S-panel L2-resident across concurrent row-blocks.
__global__ __launch_bounds__(256) void za_add_kernel(
    const float* __restrict__ Sl, const int* __restrict__ zidx,
    const float* __restrict__ zval, float* zaA, float* zaB, float* zaC)
{
    __shared__ int   pidx[128][KSP];   // 16 KB
    __shared__ float pval[128][KSP];   // 16 KB

    const int t  = threadIdx.x;
    const int r0 = blockIdx.x * 128;   // row group (fast dim)
    const int c0 = blockIdx.y * 256;   // column panel (slow dim -> L2 reuse)

    for (int i = t; i < 128 * KSP; i += 256) {
        int r = i >> 5, k = i & 31;
        pidx[r][k] = zidx[(size_t)(r0 + r) * KSP + k];
        pval[r][k] = zval[(size_t)(r0 + r) * KSP + k];
    }
    __syncthreads();

    const int rg = t >> 6;            // 0..3 -> rows rg*32 .. rg*32+31
    const int cq = (t & 63) * 4;      // 4 consecutive cols

    for (int rr = 0; rr < 32; ++rr) {
        const int r = rg * 32 + rr;
        float4 za = make_float4(0.f, 0.f, 0.f, 0.f);
        for (int k = 0; k < KSP; ++k) {           // ascending-index fold
            int   j = pidx[r][k];
            float v = pval[r][k];
            float4 s = *(const float4*)&Sl[(size_t)j * CODE_DIM + c0 + cq];
            za.x = fmaf(v, s.x, za.x);
            za.y = fmaf(v, s.y, za.y);
            za.z = fmaf(v, s.z, za.z);
            za.w = fmaf(v, s.w, za.w);
        }
        float* zap = za_row(zaA, zaB, zaC, r0 + r);
        *(float4*)&zap[c0 + cq] = za;             // exact za
    }
}

// ---------------------------------------------------------------------------
// TOPK40 v4: keys in f32 = |dequant(bf16 xw) + za| (r23-validated key math),
// AND capture each winner's exact za (r21-validated static-predicated extract)
// -> cza[40], so refine reads 160 B/row instead of 40 random 64 B lines.
__global__ __launch_bounds__(256) void topk40_kernel(
    const unsigned short* __restrict__ u, float* zaA, float* zaB, float* zaC,
    int* __restrict__ cidx, float* __restrict__ cza, int has_sparse)
{
    const int lane = threadIdx.x & 63;
    const int row  = blockIdx.x * 4 + (threadIdx.x >> 6);
    const unsigned short* ur = u + (size_t)row * CODE_DIM + lane * 32;

    float zal[32];
    if (has_sparse) {
        const float* zap = za_row(zaA, zaB, zaC, row) + lane * 32;
        #pragma unroll
        for (int q = 0; q < 8; ++q) {
            float4 zv = *(const float4*)&zap[q * 4];
            zal[q * 4 + 0] = zv.x;
            zal[q * 4 + 1] = zv.y;
            zal[q * 4 + 2] = zv.z;
            zal[q * 4 + 3] = zv.w;
        }
    } else {
        #pragma unroll
        for (int i = 0; i < 32; ++i) zal[i] = 0.f;
    }

    uint32_t a[32];
    {
        float f;
#define KEY2(word, base)                                                      \
        f = __uint_as_float((uint32_t)(word) << 16) + zal[base];              \
        a[base] = (__float_as_uint(f) & 0x7fffffffu) + 1u;                    \
        f = __uint_as_float((uint32_t)(word) & 0xffff0000u) + zal[(base) + 1];\
        a[(base) + 1] = (__float_as_uint(f) & 0x7fffffffu) + 1u;
        #pragma unroll
        for (int q = 0; q < 4; ++q) {
            uint4 v = *(const uint4*)&ur[q * 8];
            KEY2(v.x, q * 8 + 0)
            KEY2(v.y, q * 8 + 2)
            KEY2(v.z, q * 8 + 4)
            KEY2(v.w, q * 8 + 6)
        }
#undef KEY2
    }

    uint32_t wi  = 0xFFFFFFFFu;
    float    wza = 0.f;
    for (int it = 0; it < NCAND; ++it) {
        uint32_t t0[16], t1[8], t2[4], t3[2];
        #pragma unroll
        for (int j = 0; j < 16; ++j) t0[j] = a[2*j]  > a[2*j+1]  ? a[2*j]  : a[2*j+1];
        #pragma unroll
        for (int j = 0; j < 8;  ++j) t1[j] = t0[2*j] > t0[2*j+1] ? t0[2*j] : t0[2*j+1];
        #pragma unroll
        for (int j = 0; j < 4;  ++j) t2[j] = t1[2*j] > t1[2*j+1] ? t1[2*j] : t1[2*j+1];
        #pragma unroll
        for (int j = 0; j < 2;  ++j) t3[j] = t2[2*j] > t2[2*j+1] ? t2[2*j] : t2[2*j+1];
        const uint32_t mloc = t3[0] > t3[1] ? t3[0] : t3[1];

        uint32_t gmax = mloc;
        #pragma unroll
        for (int off = 1; off <= 32; off <<= 1) {
            uint32_t og = __shfl_xor(gmax, off);
            gmax = og > gmax ? og : gmax;
        }

        unsigned long long bal = __ballot(mloc == gmax);
        int owner = __ffsll(bal) - 1;

        int bj = 0;
        #pragma unroll
        for (int j = 31; j >= 0; --j)
            if (a[j] == gmax) bj = j;                 // lane's own first match
        float zsel = 0.f;
        #pragma unroll
        for (int j = 0; j < 32; ++j)                  // static predicated extract
            if (j == bj) zsel = zal[j];

        int   bjo = __shfl(bj, owner);
        float zo  = __shfl(zsel, owner);

        uint32_t gidx = (uint32_t)owner * 32u + (uint32_t)bjo;
        if (lane == it) { wi = gidx; wza = zo; }

        if (lane == owner) {
            #pragma unroll
            for (int j = 0; j < 32; ++j)
                if (j == bjo) a[j] = 0u;
        }
    }

    if (lane < NCAND) {
        cidx[(size_t)row * NCAND + lane] = (int)wi;
        cza [(size_t)row * NCAND + lane] = wza;
    }
}

// ---------------------------------------------------------------------------
// REFINE (cza path, r21-validated): exact xW chain + single add of the
// candidate's exact za scalar (contiguous read).
__global__ __launch_bounds__(256) void refine_cza_kernel(
    const float* __restrict__ x, const float* __restrict__ WT,
    const int* __restrict__ cidx, const float* __restrict__ cza,
    int* __restrict__ zidx, float* __restrict__ zval, int has_sparse)
{
    __shared__ float xs[4][INPUT_DIM];

    const int t    = threadIdx.x;
    const int lane = t & 63;
    const int w    = t >> 6;
    const int row  = blockIdx.x * 4 + w;

    const float* xr = x + (size_t)row * INPUT_DIM;
    #pragma unroll
    for (int i = 0; i < 2; ++i)
        *(float4*)&xs[w][(lane + i * 64) * 4] = *(const float4*)&xr[(lane + i * 64) * 4];
    __syncthreads();

    int   c = 0x7fffffff;
    float a = 0.f;
    if (lane < NCAND) {
        c = cidx[(size_t)row * NCAND + lane];
        const float* wc = WT + (size_t)c * INPUT_DIM;
        #pragma unroll 8
        for (int kq = 0; kq < INPUT_DIM / 4; ++kq) {       // k strictly ascending
            float4 wv = *(const float4*)&wc[kq * 4];
            float4 xv = *(const float4*)&xs[w][kq * 4];
            a = fmaf(xv.x, wv.x, a);
            a = fmaf(xv.y, wv.y, a);
            a = fmaf(xv.z, wv.z, a);
            a = fmaf(xv.w, wv.w, a);
        }
        if (has_sparse)
            a = a + cza[(size_t)row * NCAND + lane];       // single add: u = xw + zs
    }

    uint32_t key = (lane < NCAND) ? ((__float_as_uint(a) & 0x7fffffffu) + 1u) : 0u;

    uint32_t wi = 0u;
    for (int it = 0; it < KSP; ++it) {
        uint32_t bk = key;
        uint32_t bc = (key != 0u) ? (uint32_t)c : 0x7fffffffu;
        #pragma unroll
        for (int off = 1; off <= 32; off <<= 1) {
            uint32_t ok = (uint32_t)__shfl_xor((int)bk, off);
            uint32_t oc = (uint32_t)__shfl_xor((int)bc, off);
            if (ok > bk || (ok == bk && oc < bc)) { bk = ok; bc = oc; }
        }
        if (lane == it) wi = bc;
        if (key != 0u && (uint32_t)c == bc) key = 0u;
    }

    float va = 0.f;
    #pragma unroll
    for (int m = 0; m < NCAND; ++m) {
        uint32_t cm = (uint32_t)__shfl(c, m);
        float    am = __shfl(a, m);
        if (lane < KSP && wi == cm) va = am;
    }

    int rank = 0;
    #pragma unroll
    for (int m = 0; m < KSP; ++m) {
        uint32_t om = (uint32_t)__shfl((int)wi, m);
        rank += (om < wi) ? 1 : 0;
    }
    if (lane < KSP) {
        zidx[(size_t)row * KSP + rank] = (int)wi;
        zval[(size_t)row * KSP + rank] = va;
    }
}

// ---------------------------------------------------------------------------
// FALLBACK (ws too small): r16 f32 gemm (84 VGPR, spill-free)
__global__ __launch_bounds__(256) void gemm_layer_kernel(
    const float* __restrict__ x, const float* __restrict__ Wl,
    const float* __restrict__ Sl, const int* __restrict__ zidx,
    const float* __restrict__ zval, float* __restrict__ u)
{
    __shared__ float As[32][128 + 4];

    const int t   = threadIdx.x;
    const int c0  = blockIdx.x * 128;
    const int r0  = blockIdx.y * 128;
    const int tm0 = (t >> 4) * 8;
    const int cn  = (t & 15) * 4;

    float acc[8][8];
    #pragma unroll
    for (int i = 0; i < 8; ++i)
        #pragma unroll
        for (int j = 0; j < 8; ++j) acc[i][j] = 0.f;

    for (int kt = 0; kt < INPUT_DIM; kt += 32) {
        #pragma unroll
        for (int i = 0; i < 4; ++i) {
            int f   = t * 4 + i;
            int row = f >> 3, kq = f & 7;
            float4 v = *(const float4*)&x[(size_t)(r0 + row) * INPUT_DIM + kt + kq * 4];
            As[kq * 4 + 0][row] = v.x;
            As[kq * 4 + 1][row] = v.y;
            As[kq * 4 + 2][row] = v.z;
            As[kq * 4 + 3][row] = v.w;
        }
        __syncthreads();
        const float* Wb = Wl + (size_t)kt * CODE_DIM + c0 + cn;
        #pragma unroll 4
        for (int kk = 0; kk < 32; ++kk) {
            float av[8], bv[8];
            *(float4*)&av[0] = *(const float4*)&As[kk][tm0];
            *(float4*)&av[4] = *(const float4*)&As[kk][tm0 + 4];
            const float* brow = Wb + (size_t)kk * CODE_DIM;
            *(float4*)&bv[0] = *(const float4*)&brow[0];
            *(float4*)&bv[4] = *(const float4*)&brow[64];
            #pragma unroll
            for (int i = 0; i < 8; ++i)
                #pragma unroll
                for (int j = 0; j < 8; ++j)
                    acc[i][j] = fmaf(av[i], bv[j], acc[i][j]);
        }
        __syncthreads();
    }

    if (Sl != nullptr) {
        #pragma unroll
        for (int i = 0; i < 8; ++i) {
            const int r = r0 + tm0 + i;
            const int*   ip = zidx + (size_t)r * KSP;
            const float* vp = zval + (size_t)r * KSP;
            float zacc[8];
            #pragma unroll
            for (int j = 0; j < 8; ++j) zacc[j] = 0.f;
            for (int k = 0; k < KSP; ++k) {
                int   j = ip[k];
                float v = vp[k];
                const float* srow = Sl + (size_t)j * CODE_DIM + c0 + cn;
                float4 s0 = *(const float4*)&srow[0];
                float4 s1 = *(const float4*)&srow[64];
                zacc[0] = fmaf(v, s0.x, zacc[0]);
                zacc[1] = fmaf(v, s0.y, zacc[1]);
                zacc[2] = fmaf(v, s0.z, zacc[2]);
                zacc[3] = fmaf(v, s0.w, zacc[3]);
                zacc[4] = fmaf(v, s1.x, zacc[4]);
                zacc[5] = fmaf(v, s1.y, zacc[5]);
                zacc[6] = fmaf(v, s1.z, zacc[6]);
                zacc[7] = fmaf(v, s1.w, zacc[7]);
            }
            #pragma unroll
            for (int j = 0; j < 8; ++j)
                acc[i][j] = acc[i][j] + zacc[j];
        }
    }

    #pragma unroll
    for (int i = 0; i < 8; ++i) {
        float* up = u + (size_t)(r0 + tm0 + i) * CODE_DIM + c0 + cn;
        *(float4*)&up[0]  = make_float4(acc[i][0], acc[i][1], acc[i][2], acc[i][3]);
        *(float4*)&up[64] = make_float4(acc[i][4], acc[i][5], acc[i][6], acc[i][7]);
    }
}

// ---------------------------------------------------------------------------
// FALLBACK top-32 on f32 u (exact, index-sorted output) — r12 kernel
__global__ __launch_bounds__(256) void topk32_wave_kernel(const float* __restrict__ u,
                                                          int* __restrict__ zidx,
                                                          float* __restrict__ zval)
{
    const int lane = threadIdx.x & 63;
    const int row  = blockIdx.x * 4 + (threadIdx.x >> 6);
    const float* ur = u + (size_t)row * CODE_DIM;

    uint32_t a[32];
    #pragma unroll
    for (int q = 0; q < 8; ++q) {
        float4 v = *(const float4*)&ur[lane * 32 + q * 4];
        a[q * 4 + 0] = (__float_as_uint(v.x) & 0x7fffffffu) + 1u;
        a[q * 4 + 1] = (__float_as_uint(v.y) & 0x7fffffffu) + 1u;
        a[q * 4 + 2] = (__float_as_uint(v.z) & 0x7fffffffu) + 1u;
        a[q * 4 + 3] = (__float_as_uint(v.w) & 0x7fffffffu) + 1u;
    }

    uint32_t wi = 0xFFFFFFFFu;
    for (int it = 0; it < KSP; ++it) {
        uint32_t t0[16], t1[8], t2[4], t3[2];
        #pragma unroll
        for (int j = 0; j < 16; ++j) t0[j] = a[2*j]  > a[2*j+1]  ? a[2*j]  : a[2*j+1];
        #pragma unroll
        for (int j = 0; j < 8;  ++j) t1[j] = t0[2*j] > t0[2*j+1] ? t0[2*j] : t0[2*j+1];
        #pragma unroll
        for (int j = 0; j < 4;  ++j) t2[j] = t1[2*j] > t1[2*j+1] ? t1[2*j] : t1[2*j+1];
        #pragma unroll
        for (int j = 0; j < 2;  ++j) t3[j] = t2[2*j] > t2[2*j+1] ? t2[2*j] : t2[2*j+1];
        const uint32_t mloc = t3[0] > t3[1] ? t3[0] : t3[1];

        uint32_t g = mloc;
        #pragma unroll
        for (int off = 1; off <= 32; off <<= 1) {
            uint32_t og = __shfl_xor(g, off);
            g = og > g ? og : g;
        }
        unsigned long long bal = __ballot(mloc == g);
        int owner = __ffsll(bal) - 1;
        int bj = 0;
        #pragma unroll
        for (int j = 31; j >= 0; --j)
            if (a[j] == g) bj = j;
        int bjo = __shfl(bj, owner);
        uint32_t gidx = (uint32_t)owner * 32u + (uint32_t)bjo;
        if (lane == it) wi = gidx;
        if (lane == owner) {
            #pragma unroll
            for (int j = 0; j < 32; ++j)
                if (j == bjo) a[j] = 0u;
        }
    }

    int rank = 0;
    #pragma unroll
    for (int m = 0; m < 32; ++m) {
        uint32_t om = __shfl(wi, m);
        rank += (om < wi) ? 1 : 0;
    }
    if (lane < KSP) {
        int idx = (int)wi;
        zidx[(size_t)row * KSP + rank] = idx;
        zval[(size_t)row * KSP + rank] = ur[idx];
    }
}

// ---------------------------------------------------------------------------
__global__ __launch_bounds__(256) void zfill_scatter_kernel(const int* __restrict__ zidx,
                                                            const float* __restrict__ zval,
                                                            float* __restrict__ zden)
{
    const int t  = threadIdx.x;
    const int r0 = blockIdx.x * 8;
    float* base = zden + (size_t)r0 * CODE_DIM;
    const float4 zero = make_float4(0.f, 0.f, 0.f, 0.f);
    for (int q = t; q < 8 * CODE_DIM / 4; q += 256)
        *(float4*)&base[q * 4] = zero;
    __syncthreads();
    const int rl = t >> 5, k = t & 31;
    int   idx = zidx[(size_t)(r0 + rl) * KSP + k];
    float v   = zval[(size_t)(r0 + rl) * KSP + k];
    base[(size_t)rl * CODE_DIM + idx] = v;
}

// ---------------------------------------------------------------------------
__global__ __launch_bounds__(128) void recon_kernel(const int* __restrict__ zidx,
                                                    const float* __restrict__ zval,
                                                    const float* __restrict__ Dt,
                                                    float* __restrict__ recon)
{
    const int t   = threadIdx.x;
    const int row = blockIdx.x;
    float4 acc = make_float4(0.f, 0.f, 0.f, 0.f);
    const int*   ip = zidx + (size_t)row * KSP;
    const float* vp = zval + (size_t)row * KSP;
    for (int k = 0; k < KSP; ++k) {
        int   j = ip[k];
        float v = vp[k];
        float4 d = *(const float4*)&Dt[(size_t)j * INPUT_DIM + t * 4];
        acc.x = fmaf(v, d.x, acc.x);
        acc.y = fmaf(v, d.y, acc.y);
        acc.z = fmaf(v, d.z, acc.z);
        acc.w = fmaf(v, d.w, acc.w);
    }
    *(float4*)&recon[(size_t)row * INPUT_DIM + t * 4] = acc;
}

// ---------------------------------------------------------------------------
extern "C" void kernel_launch(void* const* d_in, const int* in_sizes, int n_in,
                              void* d_out, int out_size, void* d_ws, size_t ws_size,
                              hipStream_t stream)
{
    const float* x = (const float*)d_in[0];
    const float* W = (const float*)d_in[1];   // [5][512][2048]
    const float* S = (const float*)d_in[2];   // [5][2048][2048]
    const float* D = (const float*)d_in[3];   // [512][2048]

    float* recon = (float*)d_out;
    float* zden  = (float*)d_out + (size_t)BATCH * INPUT_DIM;  // u scratch, then dense z
    unsigned short* ub = (unsigned short*)zden;                // bf16 u (fast path)

    char* p = (char*)d_ws;
    int*            zidx = (int*)p;            p += (size_t)BATCH * KSP * 4;
    float*          zval = (float*)p;          p += (size_t)BATCH * KSP * 4;
    float*          Dt   = (float*)p;          p += (size_t)CODE_DIM * INPUT_DIM * 4;
    int*            cidx = (int*)p;            p += (size_t)BATCH * NCAND * 4;
    float*          cza  = (float*)p;          p += (size_t)BATCH * NCAND * 4;
    float*          WT   = (float*)p;          p += (size_t)CODE_DIM * INPUT_DIM * 4;
    unsigned short* WbT  = (unsigned short*)p; p += (size_t)CODE_DIM * INPUT_DIM * 2;
    unsigned short* xb   = (unsigned short*)p; p += (size_t)BATCH * INPUT_DIM * 2;
    float*          zaC  = (float*)p;          p += (size_t)8192 * CODE_DIM * 4;     // 67 MB
    const size_t need = (size_t)(p - (char*)d_ws);
    const bool fast = ws_size >= need;

    // za regions: A = zden second half (16384 rows), B = recon (8192), C = ws (8192)
    float* zaA = (float*)((char*)zden + (size_t)BATCH * CODE_DIM * 2);  // after bf16 u
    float* zaB = recon;

    transpose_512x2048_kernel<<<dim3(CODE_DIM / 32, INPUT_DIM / 32), dim3(32, 8), 0, stream>>>(D, Dt);

    if (fast) {
        cvt_x_kernel<<<BATCH * INPUT_DIM / (256 * 8), 256, 0, stream>>>(x, xb);
        for (int l = 0; l < LAYERS; ++l) {
            const float* Wl = W + (size_t)l * INPUT_DIM * CODE_DIM;
            const float* Sl = (l == 0) ? nullptr : S + (size_t)l * CODE_DIM * CODE_DIM;
            wt_dual_kernel<<<dim3(CODE_DIM / 32, INPUT_DIM / 32), dim3(32, 8), 0, stream>>>(Wl, WT, WbT);
            screen_kernel<<<dim3(CODE_DIM / 128, BATCH / 128), 256, 0, stream>>>(xb, WbT, ub);
            if (l > 0)
                za_add_kernel<<<dim3(BATCH / 128, CODE_DIM / 256), 256, 0, stream>>>(
                    Sl, zidx, zval, zaA, zaB, zaC);
            topk40_kernel<<<BATCH / 4, 256, 0, stream>>>(
                ub, zaA, zaB, zaC, cidx, cza, l > 0 ? 1 : 0);
            refine_cza_kernel<<<BATCH / 4, 256, 0, stream>>>(
                x, WT, cidx, cza, zidx, zval, l > 0 ? 1 : 0);
        }
    } else {
        for (int l = 0; l < LAYERS; ++l) {
            const float* Wl = W + (size_t)l * INPUT_DIM * CODE_DIM;
            const float* Sl = (l == 0) ? nullptr : S + (size_t)l * CODE_DIM * CODE_DIM;
            gemm_layer_kernel<<<dim3(CODE_DIM / 128, BATCH / 128), 256, 0, stream>>>(
                x, Wl, Sl, (l == 0) ? nullptr : zidx, (l == 0) ? nullptr : zval, zden);
            topk32_wave_kernel<<<BATCH / 4, 256, 0, stream>>>(zden, zidx, zval);
        }
    }

    zfill_scatter_kernel<<<BATCH / 8, 256, 0, stream>>>(zidx, zval, zden);
    recon_kernel<<<BATCH, 128, 0, stream>>>(zidx, zval, Dt, recon);
}

// Round 25
// 5287.294 us; speedup vs baseline: 1.0873x; 1.0873x over previous
//
#include <hip/hip_runtime.h>
#include <stdint.h>

#define LAYERS    5
#define INPUT_DIM 512
#define CODE_DIM  2048
#define BATCH     32768
#define KSP       32
#define NCAND     40

typedef __attribute__((ext_vector_type(8))) short bf16x8;
typedef __attribute__((ext_vector_type(4))) float f32x4;

__device__ __forceinline__ unsigned short f2bf(float f) {
    uint32_t u = __float_as_uint(f);
    uint32_t r = (u + 0x7fffu + ((u >> 16) & 1u)) >> 16;   // RNE
    return (unsigned short)r;
}

// za region select: rows [0,16384) -> zaA, [16384,24576) -> zaB, rest -> zaC
__device__ __forceinline__ float* za_row(float* zaA, float* zaB, float* zaC, int row) {
    return (row < 16384) ? zaA + (size_t)row * CODE_DIM
         : (row < 24576) ? zaB + (size_t)(row - 16384) * CODE_DIM
                         : zaC + (size_t)(row - 24576) * CODE_DIM;
}

#define GLOAD_LDS16(dst, src) \
    __builtin_amdgcn_global_load_lds((const __attribute__((address_space(1))) uint32_t*)(src), \
                                     (__attribute__((address_space(3))) uint32_t*)(dst), 16, 0, 0)

// ---------------------------------------------------------------------------
// src [512][2048] f32 -> dst [2048][512] f32  (bit copy; used for Dt)
__global__ __launch_bounds__(256) void transpose_512x2048_kernel(const float* __restrict__ src,
                                                                 float* __restrict__ dst)
{
    __shared__ float tile[32][33];
    const int tx = threadIdx.x;
    const int ty = threadIdx.y;
    const int cb = blockIdx.x * 32;
    const int ib = blockIdx.y * 32;
    #pragma unroll
    for (int j = 0; j < 32; j += 8)
        tile[ty + j][tx] = src[(size_t)(ib + ty + j) * CODE_DIM + cb + tx];
    __syncthreads();
    #pragma unroll
    for (int j = 0; j < 32; j += 8)
        dst[(size_t)(cb + ty + j) * INPUT_DIM + ib + tx] = tile[tx][ty + j];
}

// ---------------------------------------------------------------------------
// W [512][2048] f32 -> WT [2048][512] f32 AND WbT [2048][512] bf16 (one pass)
__global__ __launch_bounds__(256) void wt_dual_kernel(const float* __restrict__ src,
                                                      float* __restrict__ wt,
                                                      unsigned short* __restrict__ wbt)
{
    __shared__ float tile[32][33];
    const int tx = threadIdx.x;
    const int ty = threadIdx.y;
    const int cb = blockIdx.x * 32;
    const int ib = blockIdx.y * 32;
    #pragma unroll
    for (int j = 0; j < 32; j += 8)
        tile[ty + j][tx] = src[(size_t)(ib + ty + j) * CODE_DIM + cb + tx];
    __syncthreads();
    #pragma unroll
    for (int j = 0; j < 32; j += 8) {
        float v = tile[tx][ty + j];
        wt [(size_t)(cb + ty + j) * INPUT_DIM + ib + tx] = v;
        wbt[(size_t)(cb + ty + j) * INPUT_DIM + ib + tx] = f2bf(v);
    }
}

// ---------------------------------------------------------------------------
// x f32 [32768*512] -> xb bf16 (8 elems/thread)
__global__ __launch_bounds__(256) void cvt_x_kernel(const float* __restrict__ s,
                                                    unsigned short* __restrict__ d)
{
    const size_t base = ((size_t)blockIdx.x * 256 + threadIdx.x) * 8;
    float4 a = *(const float4*)&s[base];
    float4 b = *(const float4*)&s[base + 4];
    uint4 o;
    o.x = (uint32_t)f2bf(a.x) | ((uint32_t)f2bf(a.y) << 16);
    o.y = (uint32_t)f2bf(a.z) | ((uint32_t)f2bf(a.w) << 16);
    o.z = (uint32_t)f2bf(b.x) | ((uint32_t)f2bf(b.y) << 16);
    o.w = (uint32_t)f2bf(b.z) | ((uint32_t)f2bf(b.w) << 16);
    *(uint4*)&d[base] = o;
}

// ---------------------------------------------------------------------------
// SCREEN (pure bf16 MFMA xW).  Double-buffered gload-only LDS staging.
// Fragment maps validated r17.
__global__ __launch_bounds__(256) void screen_kernel(
    const unsigned short* __restrict__ xb, const unsigned short* __restrict__ WbT,
    unsigned short* __restrict__ u)
{
    __shared__ unsigned short Ash[2][128][32];   // 16 KB, gload dest (linear)
    __shared__ unsigned short Bsh[2][128][32];   // 16 KB

    const int t    = threadIdx.x;
    const int lane = t & 63;
    const int w    = t >> 6;
    const int m16  = lane & 15;
    const int g    = lane >> 4;
    const int c0   = blockIdx.x * 128;
    const int r0   = blockIdx.y * 128;

    const int srow  = lane >> 2;              // 0..15
    const int spart = (lane & 3) * 8;         // short offset within row

#define GLOAD_T(B, KT)                                                        \
    GLOAD_LDS16(&Ash[B][w * 32][0],                                           \
        xb  + (size_t)(r0 + w * 32 + srow) * INPUT_DIM + (KT) + spart);       \
    GLOAD_LDS16(&Ash[B][w * 32 + 16][0],                                      \
        xb  + (size_t)(r0 + w * 32 + 16 + srow) * INPUT_DIM + (KT) + spart);  \
    GLOAD_LDS16(&Bsh[B][w * 32][0],                                           \
        WbT + (size_t)(c0 + w * 32 + srow) * INPUT_DIM + (KT) + spart);       \
    GLOAD_LDS16(&Bsh[B][w * 32 + 16][0],                                      \
        WbT + (size_t)(c0 + w * 32 + 16 + srow) * INPUT_DIM + (KT) + spart);

#define COMPUTE_T(B)                                                          \
    {                                                                         \
        bf16x8 af0 = *(const bf16x8*)&Ash[B][w * 32 + m16][g * 8];            \
        bf16x8 af1 = *(const bf16x8*)&Ash[B][w * 32 + 16 + m16][g * 8];       \
        _Pragma("unroll")                                                     \
        for (int ns = 0; ns < 8; ++ns) {                                      \
            bf16x8 bfv = *(const bf16x8*)&Bsh[B][ns * 16 + m16][g * 8];       \
            acc[0][ns] = __builtin_amdgcn_mfma_f32_16x16x32_bf16(af0, bfv, acc[0][ns], 0, 0, 0); \
            acc[1][ns] = __builtin_amdgcn_mfma_f32_16x16x32_bf16(af1, bfv, acc[1][ns], 0, 0, 0); \
        }                                                                     \
    }

    f32x4 acc[2][8];
    #pragma unroll
    for (int mr = 0; mr < 2; ++mr)
        #pragma unroll
        for (int ns = 0; ns < 8; ++ns) acc[mr][ns] = (f32x4){0.f, 0.f, 0.f, 0.f};

    GLOAD_T(0, 0);
    __syncthreads();

    for (int kt = 0; kt < INPUT_DIM; kt += 64) {
        GLOAD_T(1, kt + 32);
        COMPUTE_T(0);
        __syncthreads();
        if (kt + 64 < INPUT_DIM) {
            GLOAD_T(0, kt + 64);
        }
        COMPUTE_T(1);
        __syncthreads();
    }

#undef GLOAD_T
#undef COMPUTE_T

    #pragma unroll
    for (int mr = 0; mr < 2; ++mr)
        #pragma unroll
        for (int ns = 0; ns < 8; ++ns)
            #pragma unroll
            for (int q = 0; q < 4; ++q) {
                const int row = r0 + w * 32 + mr * 16 + g * 4 + q;
                u[(size_t)row * CODE_DIM + c0 + ns * 16 + m16] = f2bf(acc[mr][ns][q]);
            }
}

// ---------------------------------------------------------------------------
// ZA_ADD: block-parallel exact za (contract chain: zero-init, ascending-index
// fold, f32 fmaf) for 128 rows x 256 cols per block.  Dense za only.
// Grid: blockIdx.x = row group (fast), blockIdx.y = column panel (slow) ->
// 2 MB S-panel L2-resident across concurrent row-blocks.
__global__ __launch_bounds__(256) void za_add_kernel(
    const float* __restrict__ Sl, const int* __restrict__ zidx,
    const float* __restrict__ zval, float* zaA, float* zaB, float* zaC)
{
    __shared__ int   pidx[128][KSP];   // 16 KB
    __shared__ float pval[128][KSP];   // 16 KB

    const int t  = threadIdx.x;
    const int r0 = blockIdx.x * 128;   // row group (fast dim)
    const int c0 = blockIdx.y * 256;   // column panel (slow dim -> L2 reuse)

    for (int i = t; i < 128 * KSP; i += 256) {
        int r = i >> 5, k = i & 31;
        pidx[r][k] = zidx[(size_t)(r0 + r) * KSP + k];
        pval[r][k] = zval[(size_t)(r0 + r) * KSP + k];
    }
    __syncthreads();

    const int rg = t >> 6;            // 0..3 -> rows rg*32 .. rg*32+31
    const int cq = (t & 63) * 4;      // 4 consecutive cols

    for (int rr = 0; rr < 32; ++rr) {
        const int r = rg * 32 + rr;
        float4 za = make_float4(0.f, 0.f, 0.f, 0.f);
        for (int k = 0; k < KSP; ++k) {           // ascending-index fold
            int   j = pidx[r][k];
            float v = pval[r][k];
            float4 s = *(const float4*)&Sl[(size_t)j * CODE_DIM + c0 + cq];
            za.x = fmaf(v, s.x, za.x);
            za.y = fmaf(v, s.y, za.y);
            za.z = fmaf(v, s.z, za.z);
            za.w = fmaf(v, s.w, za.w);
        }
        float* zap = za_row(zaA, zaB, zaC, r0 + r);
        *(float4*)&zap[c0 + cq] = za;             // exact za
    }
}

// ---------------------------------------------------------------------------
// TOPK40 (r23-validated): keys in f32 = |dequant(bf16 xw) + za|.
// One wave per row; key tree + ballot owner-select.  No za capture (r24
// lesson: the per-iteration extract VALU-saturates this kernel).
__global__ __launch_bounds__(256) void topk40_kernel(
    const unsigned short* __restrict__ u, float* zaA, float* zaB, float* zaC,
    int* __restrict__ cidx, int has_sparse)
{
    const int lane = threadIdx.x & 63;
    const int row  = blockIdx.x * 4 + (threadIdx.x >> 6);
    const unsigned short* ur = u + (size_t)row * CODE_DIM + lane * 32;

    float zal[32];
    if (has_sparse) {
        const float* zap = za_row(zaA, zaB, zaC, row) + lane * 32;
        #pragma unroll
        for (int q = 0; q < 8; ++q) {
            float4 zv = *(const float4*)&zap[q * 4];
            zal[q * 4 + 0] = zv.x;
            zal[q * 4 + 1] = zv.y;
            zal[q * 4 + 2] = zv.z;
            zal[q * 4 + 3] = zv.w;
        }
    } else {
        #pragma unroll
        for (int i = 0; i < 32; ++i) zal[i] = 0.f;
    }

    uint32_t a[32];
    {
        float f;
#define KEY2(word, base)                                                      \
        f = __uint_as_float((uint32_t)(word) << 16) + zal[base];              \
        a[base] = (__float_as_uint(f) & 0x7fffffffu) + 1u;                    \
        f = __uint_as_float((uint32_t)(word) & 0xffff0000u) + zal[(base) + 1];\
        a[(base) + 1] = (__float_as_uint(f) & 0x7fffffffu) + 1u;
        #pragma unroll
        for (int q = 0; q < 4; ++q) {
            uint4 v = *(const uint4*)&ur[q * 8];
            KEY2(v.x, q * 8 + 0)
            KEY2(v.y, q * 8 + 2)
            KEY2(v.z, q * 8 + 4)
            KEY2(v.w, q * 8 + 6)
        }
#undef KEY2
    }

    uint32_t wi = 0xFFFFFFFFu;
    for (int it = 0; it < NCAND; ++it) {
        uint32_t t0[16], t1[8], t2[4], t3[2];
        #pragma unroll
        for (int j = 0; j < 16; ++j) t0[j] = a[2*j]  > a[2*j+1]  ? a[2*j]  : a[2*j+1];
        #pragma unroll
        for (int j = 0; j < 8;  ++j) t1[j] = t0[2*j] > t0[2*j+1] ? t0[2*j] : t0[2*j+1];
        #pragma unroll
        for (int j = 0; j < 4;  ++j) t2[j] = t1[2*j] > t1[2*j+1] ? t1[2*j] : t1[2*j+1];
        #pragma unroll
        for (int j = 0; j < 2;  ++j) t3[j] = t2[2*j] > t2[2*j+1] ? t2[2*j] : t2[2*j+1];
        const uint32_t mloc = t3[0] > t3[1] ? t3[0] : t3[1];

        uint32_t gmax = mloc;
        #pragma unroll
        for (int off = 1; off <= 32; off <<= 1) {
            uint32_t og = __shfl_xor(gmax, off);
            gmax = og > gmax ? og : gmax;
        }

        unsigned long long bal = __ballot(mloc == gmax);
        int owner = __ffsll(bal) - 1;

        int bj = 0;
        #pragma unroll
        for (int j = 31; j >= 0; --j)
            if (a[j] == gmax) bj = j;
        int bjo = __shfl(bj, owner);

        uint32_t gidx = (uint32_t)owner * 32u + (uint32_t)bjo;
        if (lane == it) wi = gidx;

        if (lane == owner) {
            #pragma unroll
            for (int j = 0; j < 32; ++j)
                if (j == bjo) a[j] = 0u;
        }
    }

    if (lane < NCAND) cidx[(size_t)row * NCAND + lane] = (int)wi;
}

// ---------------------------------------------------------------------------
// REFINE (za-LDS path): exact xW chain + single add of the exact za element.
// za row (8 KB) staged cooperatively into LDS (coalesced float4 stream)
// instead of 40 random 64 B HBM lines; added value bit-identical.
__global__ __launch_bounds__(256) void refine_za_kernel(
    const float* __restrict__ x, const float* __restrict__ WT,
    float* zaA, float* zaB, float* zaC, const int* __restrict__ cidx,
    int* __restrict__ zidx, float* __restrict__ zval, int has_sparse)
{
    __shared__ float xs[4][INPUT_DIM];    // 8 KB
    __shared__ float zs[4][CODE_DIM];     // 32 KB

    const int t    = threadIdx.x;
    const int lane = t & 63;
    const int w    = t >> 6;
    const int row  = blockIdx.x * 4 + w;

    const float* xr = x + (size_t)row * INPUT_DIM;
    #pragma unroll
    for (int i = 0; i < 2; ++i)
        *(float4*)&xs[w][(lane + i * 64) * 4] = *(const float4*)&xr[(lane + i * 64) * 4];
    if (has_sparse) {
        const float* zap = za_row(zaA, zaB, zaC, row);
        #pragma unroll
        for (int i = 0; i < 8; ++i)       // 512 float4s per row, 64 lanes x 8
            *(float4*)&zs[w][(lane + i * 64) * 4] = *(const float4*)&zap[(lane + i * 64) * 4];
    }
    __syncthreads();

    int   c = 0x7fffffff;
    float a = 0.f;
    if (lane < NCAND) {
        c = cidx[(size_t)row * NCAND + lane];
        const float* wc = WT + (size_t)c * INPUT_DIM;
        #pragma unroll 8
        for (int kq = 0; kq < INPUT_DIM / 4; ++kq) {       // k strictly ascending
            float4 wv = *(const float4*)&wc[kq * 4];
            float4 xv = *(const float4*)&xs[w][kq * 4];
            a = fmaf(xv.x, wv.x, a);
            a = fmaf(xv.y, wv.y, a);
            a = fmaf(xv.z, wv.z, a);
            a = fmaf(xv.w, wv.w, a);
        }
        if (has_sparse)
            a = a + zs[w][c];                              // single add: u = xw + zs
    }

    uint32_t key = (lane < NCAND) ? ((__float_as_uint(a) & 0x7fffffffu) + 1u) : 0u;

    uint32_t wi = 0u;
    for (int it = 0; it < KSP; ++it) {
        uint32_t bk = key;
        uint32_t bc = (key != 0u) ? (uint32_t)c : 0x7fffffffu;
        #pragma unroll
        for (int off = 1; off <= 32; off <<= 1) {
            uint32_t ok = (uint32_t)__shfl_xor((int)bk, off);
            uint32_t oc = (uint32_t)__shfl_xor((int)bc, off);
            if (ok > bk || (ok == bk && oc < bc)) { bk = ok; bc = oc; }
        }
        if (lane == it) wi = bc;
        if (key != 0u && (uint32_t)c == bc) key = 0u;
    }

    float va = 0.f;
    #pragma unroll
    for (int m = 0; m < NCAND; ++m) {
        uint32_t cm = (uint32_t)__shfl(c, m);
        float    am = __shfl(a, m);
        if (lane < KSP && wi == cm) va = am;
    }

    int rank = 0;
    #pragma unroll
    for (int m = 0; m < KSP; ++m) {
        uint32_t om = (uint32_t)__shfl((int)wi, m);
        rank += (om < wi) ? 1 : 0;
    }
    if (lane < KSP) {
        zidx[(size_t)row * KSP + rank] = (int)wi;
        zval[(size_t)row * KSP + rank] = va;
    }
}

// ---------------------------------------------------------------------------
// FALLBACK (ws too small): r16 f32 gemm (84 VGPR, spill-free)
__global__ __launch_bounds__(256) void gemm_layer_kernel(
    const float* __restrict__ x, const float* __restrict__ Wl,
    const float* __restrict__ Sl, const int* __restrict__ zidx,
    const float* __restrict__ zval, float* __restrict__ u)
{
    __shared__ float As[32][128 + 4];

    const int t   = threadIdx.x;
    const int c0  = blockIdx.x * 128;
    const int r0  = blockIdx.y * 128;
    const int tm0 = (t >> 4) * 8;
    const int cn  = (t & 15) * 4;

    float acc[8][8];
    #pragma unroll
    for (int i = 0; i < 8; ++i)
        #pragma unroll
        for (int j = 0; j < 8; ++j) acc[i][j] = 0.f;

    for (int kt = 0; kt < INPUT_DIM; kt += 32) {
        #pragma unroll
        for (int i = 0; i < 4; ++i) {
            int f   = t * 4 + i;
            int row = f >> 3, kq = f & 7;
            float4 v = *(const float4*)&x[(size_t)(r0 + row) * INPUT_DIM + kt + kq * 4];
            As[kq * 4 + 0][row] = v.x;
            As[kq * 4 + 1][row] = v.y;
            As[kq * 4 + 2][row] = v.z;
            As[kq * 4 + 3][row] = v.w;
        }
        __syncthreads();
        const float* Wb = Wl + (size_t)kt * CODE_DIM + c0 + cn;
        #pragma unroll 4
        for (int kk = 0; kk < 32; ++kk) {
            float av[8], bv[8];
            *(float4*)&av[0] = *(const float4*)&As[kk][tm0];
            *(float4*)&av[4] = *(const float4*)&As[kk][tm0 + 4];
            const float* brow = Wb + (size_t)kk * CODE_DIM;
            *(float4*)&bv[0] = *(const float4*)&brow[0];
            *(float4*)&bv[4] = *(const float4*)&brow[64];
            #pragma unroll
            for (int i = 0; i < 8; ++i)
                #pragma unroll
                for (int j = 0; j < 8; ++j)
                    acc[i][j] = fmaf(av[i], bv[j], acc[i][j]);
        }
        __syncthreads();
    }

    if (Sl != nullptr) {
        #pragma unroll
        for (int i = 0; i < 8; ++i) {
            const int r = r0 + tm0 + i;
            const int*   ip = zidx + (size_t)r * KSP;
            const float* vp = zval + (size_t)r * KSP;
            float zacc[8];
            #pragma unroll
            for (int j = 0; j < 8; ++j) zacc[j] = 0.f;
            for (int k = 0; k < KSP; ++k) {
                int   j = ip[k];
                float v = vp[k];
                const float* srow = Sl + (size_t)j * CODE_DIM + c0 + cn;
                float4 s0 = *(const float4*)&srow[0];
                float4 s1 = *(const float4*)&srow[64];
                zacc[0] = fmaf(v, s0.x, zacc[0]);
                zacc[1] = fmaf(v, s0.y, zacc[1]);
                zacc[2] = fmaf(v, s0.z, zacc[2]);
                zacc[3] = fmaf(v, s0.w, zacc[3]);
                zacc[4] = fmaf(v, s1.x, zacc[4]);
                zacc[5] = fmaf(v, s1.y, zacc[5]);
                zacc[6] = fmaf(v, s1.z, zacc[6]);
                zacc[7] = fmaf(v, s1.w, zacc[7]);
            }
            #pragma unroll
            for (int j = 0; j < 8; ++j)
                acc[i][j] = acc[i][j] + zacc[j];
        }
    }

    #pragma unroll
    for (int i = 0; i < 8; ++i) {
        float* up = u + (size_t)(r0 + tm0 + i) * CODE_DIM + c0 + cn;
        *(float4*)&up[0]  = make_float4(acc[i][0], acc[i][1], acc[i][2], acc[i][3]);
        *(float4*)&up[64] = make_float4(acc[i][4], acc[i][5], acc[i][6], acc[i][7]);
    }
}

// ---------------------------------------------------------------------------
// FALLBACK top-32 on f32 u (exact, index-sorted output) — r12 kernel
__global__ __launch_bounds__(256) void topk32_wave_kernel(const float* __restrict__ u,
                                                          int* __restrict__ zidx,
                                                          float* __restrict__ zval)
{
    const int lane = threadIdx.x & 63;
    const int row  = blockIdx.x * 4 + (threadIdx.x >> 6);
    const float* ur = u + (size_t)row * CODE_DIM;

    uint32_t a[32];
    #pragma unroll
    for (int q = 0; q < 8; ++q) {
        float4 v = *(const float4*)&ur[lane * 32 + q * 4];
        a[q * 4 + 0] = (__float_as_uint(v.x) & 0x7fffffffu) + 1u;
        a[q * 4 + 1] = (__float_as_uint(v.y) & 0x7fffffffu) + 1u;
        a[q * 4 + 2] = (__float_as_uint(v.z) & 0x7fffffffu) + 1u;
        a[q * 4 + 3] = (__float_as_uint(v.w) & 0x7fffffffu) + 1u;
    }

    uint32_t wi = 0xFFFFFFFFu;
    for (int it = 0; it < KSP; ++it) {
        uint32_t t0[16], t1[8], t2[4], t3[2];
        #pragma unroll
        for (int j = 0; j < 16; ++j) t0[j] = a[2*j]  > a[2*j+1]  ? a[2*j]  : a[2*j+1];
        #pragma unroll
        for (int j = 0; j < 8;  ++j) t1[j] = t0[2*j] > t0[2*j+1] ? t0[2*j] : t0[2*j+1];
        #pragma unroll
        for (int j = 0; j < 4;  ++j) t2[j] = t1[2*j] > t1[2*j+1] ? t1[2*j] : t1[2*j+1];
        #pragma unroll
        for (int j = 0; j < 2;  ++j) t3[j] = t2[2*j] > t2[2*j+1] ? t2[2*j] : t2[2*j+1];
        const uint32_t mloc = t3[0] > t3[1] ? t3[0] : t3[1];

        uint32_t g = mloc;
        #pragma unroll
        for (int off = 1; off <= 32; off <<= 1) {
            uint32_t og = __shfl_xor(g, off);
            g = og > g ? og : g;
        }
        unsigned long long bal = __ballot(mloc == g);
        int owner = __ffsll(bal) - 1;
        int bj = 0;
        #pragma unroll
        for (int j = 31; j >= 0; --j)
            if (a[j] == g) bj = j;
        int bjo = __shfl(bj, owner);
        uint32_t gidx = (uint32_t)owner * 32u + (uint32_t)bjo;
        if (lane == it) wi = gidx;
        if (lane == owner) {
            #pragma unroll
            for (int j = 0; j < 32; ++j)
                if (j == bjo) a[j] = 0u;
        }
    }

    int rank = 0;
    #pragma unroll
    for (int m = 0; m < 32; ++m) {
        uint32_t om = __shfl(wi, m);
        rank += (om < wi) ? 1 : 0;
    }
    if (lane < KSP) {
        int idx = (int)wi;
        zidx[(size_t)row * KSP + rank] = idx;
        zval[(size_t)row * KSP + rank] = ur[idx];
    }
}

// ---------------------------------------------------------------------------
__global__ __launch_bounds__(256) void zfill_scatter_kernel(const int* __restrict__ zidx,
                                                            const float* __restrict__ zval,
                                                            float* __restrict__ zden)
{
    const int t  = threadIdx.x;
    const int r0 = blockIdx.x * 8;
    float* base = zden + (size_t)r0 * CODE_DIM;
    const float4 zero = make_float4(0.f, 0.f, 0.f, 0.f);
    for (int q = t; q < 8 * CODE_DIM / 4; q += 256)
        *(float4*)&base[q * 4] = zero;
    __syncthreads();
    const int rl = t >> 5, k = t & 31;
    int   idx = zidx[(size_t)(r0 + rl) * KSP + k];
    float v   = zval[(size_t)(r0 + rl) * KSP + k];
    base[(size_t)rl * CODE_DIM + idx] = v;
}

// ---------------------------------------------------------------------------
__global__ __launch_bounds__(128) void recon_kernel(const int* __restrict__ zidx,
                                                    const float* __restrict__ zval,
                                                    const float* __restrict__ Dt,
                                                    float* __restrict__ recon)
{
    const int t   = threadIdx.x;
    const int row = blockIdx.x;
    float4 acc = make_float4(0.f, 0.f, 0.f, 0.f);
    const int*   ip = zidx + (size_t)row * KSP;
    const float* vp = zval + (size_t)row * KSP;
    for (int k = 0; k < KSP; ++k) {
        int   j = ip[k];
        float v = vp[k];
        float4 d = *(const float4*)&Dt[(size_t)j * INPUT_DIM + t * 4];
        acc.x = fmaf(v, d.x, acc.x);
        acc.y = fmaf(v, d.y, acc.y);
        acc.z = fmaf(v, d.z, acc.z);
        acc.w = fmaf(v, d.w, acc.w);
    }
    *(float4*)&recon[(size_t)row * INPUT_DIM + t * 4] = acc;
}

// ---------------------------------------------------------------------------
extern "C" void kernel_launch(void* const* d_in, const int* in_sizes, int n_in,
                              void* d_out, int out_size, void* d_ws, size_t ws_size,
                              hipStream_t stream)
{
    const float* x = (const float*)d_in[0];
    const float* W = (const float*)d_in[1];   // [5][512][2048]
    const float* S = (const float*)d_in[2];   // [5][2048][2048]
    const float* D = (const float*)d_in[3];   // [512][2048]

    float* recon = (float*)d_out;
    float* zden  = (float*)d_out + (size_t)BATCH * INPUT_DIM;  // u scratch, then dense z
    unsigned short* ub = (unsigned short*)zden;                // bf16 u (fast path)

    char* p = (char*)d_ws;
    int*            zidx = (int*)p;            p += (size_t)BATCH * KSP * 4;
    float*          zval = (float*)p;          p += (size_t)BATCH * KSP * 4;
    float*          Dt   = (float*)p;          p += (size_t)CODE_DIM * INPUT_DIM * 4;
    int*            cidx = (int*)p;            p += (size_t)BATCH * NCAND * 4;
    float*          WT   = (float*)p;          p += (size_t)CODE_DIM * INPUT_DIM * 4;
    unsigned short* WbT  = (unsigned short*)p; p += (size_t)CODE_DIM * INPUT_DIM * 2;
    unsigned short* xb   = (unsigned short*)p; p += (size_t)BATCH * INPUT_DIM * 2;
    float*          zaC  = (float*)p;          p += (size_t)8192 * CODE_DIM * 4;     // 67 MB
    const size_t need = (size_t)(p - (char*)d_ws);
    const bool fast = ws_size >= need;

    // za regions: A = zden second half (16384 rows), B = recon (8192), C = ws (8192)
    float* zaA = (float*)((char*)zden + (size_t)BATCH * CODE_DIM * 2);  // after bf16 u
    float* zaB = recon;

    transpose_512x2048_kernel<<<dim3(CODE_DIM / 32, INPUT_DIM / 32), dim3(32, 8), 0, stream>>>(D, Dt);

    if (fast) {
        cvt_x_kernel<<<BATCH * INPUT_DIM / (256 * 8), 256, 0, stream>>>(x, xb);
        for (int l = 0; l < LAYERS; ++l) {
            const float* Wl = W + (size_t)l * INPUT_DIM * CODE_DIM;
            const float* Sl = (l == 0) ? nullptr : S + (size_t)l * CODE_DIM * CODE_DIM;
            wt_dual_kernel<<<dim3(CODE_DIM / 32, INPUT_DIM / 32), dim3(32, 8), 0, stream>>>(Wl, WT, WbT);
            screen_kernel<<<dim3(CODE_DIM / 128, BATCH / 128), 256, 0, stream>>>(xb, WbT, ub);
            if (l > 0)
                za_add_kernel<<<dim3(BATCH / 128, CODE_DIM / 256), 256, 0, stream>>>(
                    Sl, zidx, zval, zaA, zaB, zaC);
            topk40_kernel<<<BATCH / 4, 256, 0, stream>>>(
                ub, zaA, zaB, zaC, cidx, l > 0 ? 1 : 0);
            refine_za_kernel<<<BATCH / 4, 256, 0, stream>>>(
                x, WT, zaA, zaB, zaC, cidx, zidx, zval, l > 0 ? 1 : 0);
        }
    } else {
        for (int l = 0; l < LAYERS; ++l) {
            const float* Wl = W + (size_t)l * INPUT_DIM * CODE_DIM;
            const float* Sl = (l == 0) ? nullptr : S + (size_t)l * CODE_DIM * CODE_DIM;
            gemm_layer_kernel<<<dim3(CODE_DIM / 128, BATCH / 128), 256, 0, stream>>>(
                x, Wl, Sl, (l == 0) ? nullptr : zidx, (l == 0) ? nullptr : zval, zden);
            topk32_wave_kernel<<<BATCH / 4, 256, 0, stream>>>(zden, zidx, zval);
        }
    }

    zfill_scatter_kernel<<<BATCH / 8, 256, 0, stream>>>(zidx, zval, zden);
    recon_kernel<<<BATCH, 128, 0, stream>>>(zidx, zval, Dt, recon);
}

// Round 26
// 5246.275 us; speedup vs baseline: 1.0958x; 1.0078x over previous
//
#include <hip/hip_runtime.h>
#include <stdint.h>

#define LAYERS    5
#define INPUT_DIM 512
#define CODE_DIM  2048
#define BATCH     32768
#define KSP       32
#define NCAND     40

typedef __attribute__((ext_vector_type(8))) short bf16x8;
typedef __attribute__((ext_vector_type(4))) float f32x4;

__device__ __forceinline__ unsigned short f2bf(float f) {
    uint32_t u = __float_as_uint(f);
    uint32_t r = (u + 0x7fffu + ((u >> 16) & 1u)) >> 16;   // RNE
    return (unsigned short)r;
}

// za region select: rows [0,16384) -> zaA, [16384,24576) -> zaB, rest -> zaC
__device__ __forceinline__ float* za_row(float* zaA, float* zaB, float* zaC, int row) {
    return (row < 16384) ? zaA + (size_t)row * CODE_DIM
         : (row < 24576) ? zaB + (size_t)(row - 16384) * CODE_DIM
                         : zaC + (size_t)(row - 24576) * CODE_DIM;
}

#define GLOAD_LDS16(dst, src) \
    __builtin_amdgcn_global_load_lds((const __attribute__((address_space(1))) uint32_t*)(src), \
                                     (__attribute__((address_space(3))) uint32_t*)(dst), 16, 0, 0)

// ---------------------------------------------------------------------------
// src [512][2048] f32 -> dst [2048][512] f32  (bit copy; used for Dt)
__global__ __launch_bounds__(256) void transpose_512x2048_kernel(const float* __restrict__ src,
                                                                 float* __restrict__ dst)
{
    __shared__ float tile[32][33];
    const int tx = threadIdx.x;
    const int ty = threadIdx.y;
    const int cb = blockIdx.x * 32;
    const int ib = blockIdx.y * 32;
    #pragma unroll
    for (int j = 0; j < 32; j += 8)
        tile[ty + j][tx] = src[(size_t)(ib + ty + j) * CODE_DIM + cb + tx];
    __syncthreads();
    #pragma unroll
    for (int j = 0; j < 32; j += 8)
        dst[(size_t)(cb + ty + j) * INPUT_DIM + ib + tx] = tile[tx][ty + j];
}

// ---------------------------------------------------------------------------
// W [512][2048] f32 -> WT [2048][512] f32 AND WbT [2048][512] bf16 (one pass)
__global__ __launch_bounds__(256) void wt_dual_kernel(const float* __restrict__ src,
                                                      float* __restrict__ wt,
                                                      unsigned short* __restrict__ wbt)
{
    __shared__ float tile[32][33];
    const int tx = threadIdx.x;
    const int ty = threadIdx.y;
    const int cb = blockIdx.x * 32;
    const int ib = blockIdx.y * 32;
    #pragma unroll
    for (int j = 0; j < 32; j += 8)
        tile[ty + j][tx] = src[(size_t)(ib + ty + j) * CODE_DIM + cb + tx];
    __syncthreads();
    #pragma unroll
    for (int j = 0; j < 32; j += 8) {
        float v = tile[tx][ty + j];
        wt [(size_t)(cb + ty + j) * INPUT_DIM + ib + tx] = v;
        wbt[(size_t)(cb + ty + j) * INPUT_DIM + ib + tx] = f2bf(v);
    }
}

// ---------------------------------------------------------------------------
// x f32 [32768*512] -> xb bf16 (8 elems/thread)
__global__ __launch_bounds__(256) void cvt_x_kernel(const float* __restrict__ s,
                                                    unsigned short* __restrict__ d)
{
    const size_t base = ((size_t)blockIdx.x * 256 + threadIdx.x) * 8;
    float4 a = *(const float4*)&s[base];
    float4 b = *(const float4*)&s[base + 4];
    uint4 o;
    o.x = (uint32_t)f2bf(a.x) | ((uint32_t)f2bf(a.y) << 16);
    o.y = (uint32_t)f2bf(a.z) | ((uint32_t)f2bf(a.w) << 16);
    o.z = (uint32_t)f2bf(b.x) | ((uint32_t)f2bf(b.y) << 16);
    o.w = (uint32_t)f2bf(b.z) | ((uint32_t)f2bf(b.w) << 16);
    *(uint4*)&d[base] = o;
}

// ---------------------------------------------------------------------------
// SCREEN (pure bf16 MFMA xW).  Double-buffered gload-only LDS staging.
// Fragment maps validated r17.
__global__ __launch_bounds__(256) void screen_kernel(
    const unsigned short* __restrict__ xb, const unsigned short* __restrict__ WbT,
    unsigned short* __restrict__ u)
{
    __shared__ unsigned short Ash[2][128][32];   // 16 KB, gload dest (linear)
    __shared__ unsigned short Bsh[2][128][32];   // 16 KB

    const int t    = threadIdx.x;
    const int lane = t & 63;
    const int w    = t >> 6;
    const int m16  = lane & 15;
    const int g    = lane >> 4;
    const int c0   = blockIdx.x * 128;
    const int r0   = blockIdx.y * 128;

    const int srow  = lane >> 2;              // 0..15
    const int spart = (lane & 3) * 8;         // short offset within row

#define GLOAD_T(B, KT)                                                        \
    GLOAD_LDS16(&Ash[B][w * 32][0],                                           \
        xb  + (size_t)(r0 + w * 32 + srow) * INPUT_DIM + (KT) + spart);       \
    GLOAD_LDS16(&Ash[B][w * 32 + 16][0],                                      \
        xb  + (size_t)(r0 + w * 32 + 16 + srow) * INPUT_DIM + (KT) + spart);  \
    GLOAD_LDS16(&Bsh[B][w * 32][0],                                           \
        WbT + (size_t)(c0 + w * 32 + srow) * INPUT_DIM + (KT) + spart);       \
    GLOAD_LDS16(&Bsh[B][w * 32 + 16][0],                                      \
        WbT + (size_t)(c0 + w * 32 + 16 + srow) * INPUT_DIM + (KT) + spart);

#define COMPUTE_T(B)                                                          \
    {                                                                         \
        bf16x8 af0 = *(const bf16x8*)&Ash[B][w * 32 + m16][g * 8];            \
        bf16x8 af1 = *(const bf16x8*)&Ash[B][w * 32 + 16 + m16][g * 8];       \
        _Pragma("unroll")                                                     \
        for (int ns = 0; ns < 8; ++ns) {                                      \
            bf16x8 bfv = *(const bf16x8*)&Bsh[B][ns * 16 + m16][g * 8];       \
            acc[0][ns] = __builtin_amdgcn_mfma_f32_16x16x32_bf16(af0, bfv, acc[0][ns], 0, 0, 0); \
            acc[1][ns] = __builtin_amdgcn_mfma_f32_16x16x32_bf16(af1, bfv, acc[1][ns], 0, 0, 0); \
        }                                                                     \
    }

    f32x4 acc[2][8];
    #pragma unroll
    for (int mr = 0; mr < 2; ++mr)
        #pragma unroll
        for (int ns = 0; ns < 8; ++ns) acc[mr][ns] = (f32x4){0.f, 0.f, 0.f, 0.f};

    GLOAD_T(0, 0);
    __syncthreads();

    for (int kt = 0; kt < INPUT_DIM; kt += 64) {
        GLOAD_T(1, kt + 32);
        COMPUTE_T(0);
        __syncthreads();
        if (kt + 64 < INPUT_DIM) {
            GLOAD_T(0, kt + 64);
        }
        COMPUTE_T(1);
        __syncthreads();
    }

#undef GLOAD_T
#undef COMPUTE_T

    #pragma unroll
    for (int mr = 0; mr < 2; ++mr)
        #pragma unroll
        for (int ns = 0; ns < 8; ++ns)
            #pragma unroll
            for (int q = 0; q < 4; ++q) {
                const int row = r0 + w * 32 + mr * 16 + g * 4 + q;
                u[(size_t)row * CODE_DIM + c0 + ns * 16 + m16] = f2bf(acc[mr][ns][q]);
            }
}

// ---------------------------------------------------------------------------
// ZA_ADD: block-parallel exact za (contract chain: zero-init, ascending-index
// fold, f32 fmaf) for 128 rows x 256 cols per block.  Dense za only.
// Grid: blockIdx.x = row group (fast), blockIdx.y = column panel (slow) ->
// 2 MB S-panel L2-resident across concurrent row-blocks.
__global__ __launch_bounds__(256) void za_add_kernel(
    const float* __restrict__ Sl, const int* __restrict__ zidx,
    const float* __restrict__ zval, float* zaA, float* zaB, float* zaC)
{
    __shared__ int   pidx[128][KSP];   // 16 KB
    __shared__ float pval[128][KSP];   // 16 KB

    const int t  = threadIdx.x;
    const int r0 = blockIdx.x * 128;   // row group (fast dim)
    const int c0 = blockIdx.y * 256;   // column panel (slow dim -> L2 reuse)

    for (int i = t; i < 128 * KSP; i += 256) {
        int r = i >> 5, k = i & 31;
        pidx[r][k] = zidx[(size_t)(r0 + r) * KSP + k];
        pval[r][k] = zval[(size_t)(r0 + r) * KSP + k];
    }
    __syncthreads();

    const int rg = t >> 6;            // 0..3 -> rows rg*32 .. rg*32+31
    const int cq = (t & 63) * 4;      // 4 consecutive cols

    for (int rr = 0; rr < 32; ++rr) {
        const int r = rg * 32 + rr;
        float4 za = make_float4(0.f, 0.f, 0.f, 0.f);
        for (int k = 0; k < KSP; ++k) {           // ascending-index fold
            int   j = pidx[r][k];
            float v = pval[r][k];
            float4 s = *(const float4*)&Sl[(size_t)j * CODE_DIM + c0 + cq];
            za.x = fmaf(v, s.x, za.x);
            za.y = fmaf(v, s.y, za.y);
            za.z = fmaf(v, s.z, za.z);
            za.w = fmaf(v, s.w, za.w);
        }
        float* zap = za_row(zaA, zaB, zaC, r0 + r);
        *(float4*)&zap[c0 + cq] = za;             // exact za
    }
}

// ---------------------------------------------------------------------------
// TOPK40 (r23-validated): keys in f32 = |dequant(bf16 xw) + za|.
// One wave per row; key tree + ballot owner-select.
__global__ __launch_bounds__(256) void topk40_kernel(
    const unsigned short* __restrict__ u, float* zaA, float* zaB, float* zaC,
    int* __restrict__ cidx, int has_sparse)
{
    const int lane = threadIdx.x & 63;
    const int row  = blockIdx.x * 4 + (threadIdx.x >> 6);
    const unsigned short* ur = u + (size_t)row * CODE_DIM + lane * 32;

    float zal[32];
    if (has_sparse) {
        const float* zap = za_row(zaA, zaB, zaC, row) + lane * 32;
        #pragma unroll
        for (int q = 0; q < 8; ++q) {
            float4 zv = *(const float4*)&zap[q * 4];
            zal[q * 4 + 0] = zv.x;
            zal[q * 4 + 1] = zv.y;
            zal[q * 4 + 2] = zv.z;
            zal[q * 4 + 3] = zv.w;
        }
    } else {
        #pragma unroll
        for (int i = 0; i < 32; ++i) zal[i] = 0.f;
    }

    uint32_t a[32];
    {
        float f;
#define KEY2(word, base)                                                      \
        f = __uint_as_float((uint32_t)(word) << 16) + zal[base];              \
        a[base] = (__float_as_uint(f) & 0x7fffffffu) + 1u;                    \
        f = __uint_as_float((uint32_t)(word) & 0xffff0000u) + zal[(base) + 1];\
        a[(base) + 1] = (__float_as_uint(f) & 0x7fffffffu) + 1u;
        #pragma unroll
        for (int q = 0; q < 4; ++q) {
            uint4 v = *(const uint4*)&ur[q * 8];
            KEY2(v.x, q * 8 + 0)
            KEY2(v.y, q * 8 + 2)
            KEY2(v.z, q * 8 + 4)
            KEY2(v.w, q * 8 + 6)
        }
#undef KEY2
    }

    uint32_t wi = 0xFFFFFFFFu;
    for (int it = 0; it < NCAND; ++it) {
        uint32_t t0[16], t1[8], t2[4], t3[2];
        #pragma unroll
        for (int j = 0; j < 16; ++j) t0[j] = a[2*j]  > a[2*j+1]  ? a[2*j]  : a[2*j+1];
        #pragma unroll
        for (int j = 0; j < 8;  ++j) t1[j] = t0[2*j] > t0[2*j+1] ? t0[2*j] : t0[2*j+1];
        #pragma unroll
        for (int j = 0; j < 4;  ++j) t2[j] = t1[2*j] > t1[2*j+1] ? t1[2*j] : t1[2*j+1];
        #pragma unroll
        for (int j = 0; j < 2;  ++j) t3[j] = t2[2*j] > t2[2*j+1] ? t2[2*j] : t2[2*j+1];
        const uint32_t mloc = t3[0] > t3[1] ? t3[0] : t3[1];

        uint32_t gmax = mloc;
        #pragma unroll
        for (int off = 1; off <= 32; off <<= 1) {
            uint32_t og = __shfl_xor(gmax, off);
            gmax = og > gmax ? og : gmax;
        }

        unsigned long long bal = __ballot(mloc == gmax);
        int owner = __ffsll(bal) - 1;

        int bj = 0;
        #pragma unroll
        for (int j = 31; j >= 0; --j)
            if (a[j] == gmax) bj = j;
        int bjo = __shfl(bj, owner);

        uint32_t gidx = (uint32_t)owner * 32u + (uint32_t)bjo;
        if (lane == it) wi = gidx;

        if (lane == owner) {
            #pragma unroll
            for (int j = 0; j < 32; ++j)
                if (j == bjo) a[j] = 0u;
        }
    }

    if (lane < NCAND) cidx[(size_t)row * NCAND + lane] = (int)wi;
}

// ---------------------------------------------------------------------------
// REFINE (za-gather, EARLY-issue): the za gather is issued BEFORE the xW
// chain so its ~900 cy HBM latency hides under the 512-step fmaf chain.
// Value added is the same f32 element -> bitwise-identical results (r23).
__global__ __launch_bounds__(256) void refine_za_kernel(
    const float* __restrict__ x, const float* __restrict__ WT,
    float* zaA, float* zaB, float* zaC, const int* __restrict__ cidx,
    int* __restrict__ zidx, float* __restrict__ zval, int has_sparse)
{
    __shared__ float xs[4][INPUT_DIM];    // 8 KB

    const int t    = threadIdx.x;
    const int lane = t & 63;
    const int w    = t >> 6;
    const int row  = blockIdx.x * 4 + w;

    const float* xr = x + (size_t)row * INPUT_DIM;
    #pragma unroll
    for (int i = 0; i < 2; ++i)
        *(float4*)&xs[w][(lane + i * 64) * 4] = *(const float4*)&xr[(lane + i * 64) * 4];
    __syncthreads();

    int   c = 0x7fffffff;
    float a = 0.f;
    if (lane < NCAND) {
        c = cidx[(size_t)row * NCAND + lane];
        float zav = 0.f;
        if (has_sparse) {
            const float* zap = za_row(zaA, zaB, zaC, row);
            zav = zap[c];                                  // issue gather EARLY
        }
        const float* wc = WT + (size_t)c * INPUT_DIM;
        #pragma unroll 8
        for (int kq = 0; kq < INPUT_DIM / 4; ++kq) {       // k strictly ascending
            float4 wv = *(const float4*)&wc[kq * 4];
            float4 xv = *(const float4*)&xs[w][kq * 4];
            a = fmaf(xv.x, wv.x, a);
            a = fmaf(xv.y, wv.y, a);
            a = fmaf(xv.z, wv.z, a);
            a = fmaf(xv.w, wv.w, a);
        }
        if (has_sparse)
            a = a + zav;                                   // single add: u = xw + zs
    }

    uint32_t key = (lane < NCAND) ? ((__float_as_uint(a) & 0x7fffffffu) + 1u) : 0u;

    uint32_t wi = 0u;
    for (int it = 0; it < KSP; ++it) {
        uint32_t bk = key;
        uint32_t bc = (key != 0u) ? (uint32_t)c : 0x7fffffffu;
        #pragma unroll
        for (int off = 1; off <= 32; off <<= 1) {
            uint32_t ok = (uint32_t)__shfl_xor((int)bk, off);
            uint32_t oc = (uint32_t)__shfl_xor((int)bc, off);
            if (ok > bk || (ok == bk && oc < bc)) { bk = ok; bc = oc; }
        }
        if (lane == it) wi = bc;
        if (key != 0u && (uint32_t)c == bc) key = 0u;
    }

    float va = 0.f;
    #pragma unroll
    for (int m = 0; m < NCAND; ++m) {
        uint32_t cm = (uint32_t)__shfl(c, m);
        float    am = __shfl(a, m);
        if (lane < KSP && wi == cm) va = am;
    }

    int rank = 0;
    #pragma unroll
    for (int m = 0; m < KSP; ++m) {
        uint32_t om = (uint32_t)__shfl((int)wi, m);
        rank += (om < wi) ? 1 : 0;
    }
    if (lane < KSP) {
        zidx[(size_t)row * KSP + rank] = (int)wi;
        zval[(size_t)row * KSP + rank] = va;
    }
}

// ---------------------------------------------------------------------------
// FALLBACK (ws too small): r16 f32 gemm (84 VGPR, spill-free)
__global__ __launch_bounds__(256) void gemm_layer_kernel(
    const float* __restrict__ x, const float* __restrict__ Wl,
    const float* __restrict__ Sl, const int* __restrict__ zidx,
    const float* __restrict__ zval, float* __restrict__ u)
{
    __shared__ float As[32][128 + 4];

    const int t   = threadIdx.x;
    const int c0  = blockIdx.x * 128;
    const int r0  = blockIdx.y * 128;
    const int tm0 = (t >> 4) * 8;
    const int cn  = (t & 15) * 4;

    float acc[8][8];
    #pragma unroll
    for (int i = 0; i < 8; ++i)
        #pragma unroll
        for (int j = 0; j < 8; ++j) acc[i][j] = 0.f;

    for (int kt = 0; kt < INPUT_DIM; kt += 32) {
        #pragma unroll
        for (int i = 0; i < 4; ++i) {
            int f   = t * 4 + i;
            int row = f >> 3, kq = f & 7;
            float4 v = *(const float4*)&x[(size_t)(r0 + row) * INPUT_DIM + kt + kq * 4];
            As[kq * 4 + 0][row] = v.x;
            As[kq * 4 + 1][row] = v.y;
            As[kq * 4 + 2][row] = v.z;
            As[kq * 4 + 3][row] = v.w;
        }
        __syncthreads();
        const float* Wb = Wl + (size_t)kt * CODE_DIM + c0 + cn;
        #pragma unroll 4
        for (int kk = 0; kk < 32; ++kk) {
            float av[8], bv[8];
            *(float4*)&av[0] = *(const float4*)&As[kk][tm0];
            *(float4*)&av[4] = *(const float4*)&As[kk][tm0 + 4];
            const float* brow = Wb + (size_t)kk * CODE_DIM;
            *(float4*)&bv[0] = *(const float4*)&brow[0];
            *(float4*)&bv[4] = *(const float4*)&brow[64];
            #pragma unroll
            for (int i = 0; i < 8; ++i)
                #pragma unroll
                for (int j = 0; j < 8; ++j)
                    acc[i][j] = fmaf(av[i], bv[j], acc[i][j]);
        }
        __syncthreads();
    }

    if (Sl != nullptr) {
        #pragma unroll
        for (int i = 0; i < 8; ++i) {
            const int r = r0 + tm0 + i;
            const int*   ip = zidx + (size_t)r * KSP;
            const float* vp = zval + (size_t)r * KSP;
            float zacc[8];
            #pragma unroll
            for (int j = 0; j < 8; ++j) zacc[j] = 0.f;
            for (int k = 0; k < KSP; ++k) {
                int   j = ip[k];
                float v = vp[k];
                const float* srow = Sl + (size_t)j * CODE_DIM + c0 + cn;
                float4 s0 = *(const float4*)&srow[0];
                float4 s1 = *(const float4*)&srow[64];
                zacc[0] = fmaf(v, s0.x, zacc[0]);
                zacc[1] = fmaf(v, s0.y, zacc[1]);
                zacc[2] = fmaf(v, s0.z, zacc[2]);
                zacc[3] = fmaf(v, s0.w, zacc[3]);
                zacc[4] = fmaf(v, s1.x, zacc[4]);
                zacc[5] = fmaf(v, s1.y, zacc[5]);
                zacc[6] = fmaf(v, s1.z, zacc[6]);
                zacc[7] = fmaf(v, s1.w, zacc[7]);
            }
            #pragma unroll
            for (int j = 0; j < 8; ++j)
                acc[i][j] = acc[i][j] + zacc[j];
        }
    }

    #pragma unroll
    for (int i = 0; i < 8; ++i) {
        float* up = u + (size_t)(r0 + tm0 + i) * CODE_DIM + c0 + cn;
        *(float4*)&up[0]  = make_float4(acc[i][0], acc[i][1], acc[i][2], acc[i][3]);
        *(float4*)&up[64] = make_float4(acc[i][4], acc[i][5], acc[i][6], acc[i][7]);
    }
}

// ---------------------------------------------------------------------------
// FALLBACK top-32 on f32 u (exact, index-sorted output) — r12 kernel
__global__ __launch_bounds__(256) void topk32_wave_kernel(const float* __restrict__ u,
                                                          int* __restrict__ zidx,
                                                          float* __restrict__ zval)
{
    const int lane = threadIdx.x & 63;
    const int row  = blockIdx.x * 4 + (threadIdx.x >> 6);
    const float* ur = u + (size_t)row * CODE_DIM;

    uint32_t a[32];
    #pragma unroll
    for (int q = 0; q < 8; ++q) {
        float4 v = *(const float4*)&ur[lane * 32 + q * 4];
        a[q * 4 + 0] = (__float_as_uint(v.x) & 0x7fffffffu) + 1u;
        a[q * 4 + 1] = (__float_as_uint(v.y) & 0x7fffffffu) + 1u;
        a[q * 4 + 2] = (__float_as_uint(v.z) & 0x7fffffffu) + 1u;
        a[q * 4 + 3] = (__float_as_uint(v.w) & 0x7fffffffu) + 1u;
    }

    uint32_t wi = 0xFFFFFFFFu;
    for (int it = 0; it < KSP; ++it) {
        uint32_t t0[16], t1[8], t2[4], t3[2];
        #pragma unroll
        for (int j = 0; j < 16; ++j) t0[j] = a[2*j]  > a[2*j+1]  ? a[2*j]  : a[2*j+1];
        #pragma unroll
        for (int j = 0; j < 8;  ++j) t1[j] = t0[2*j] > t0[2*j+1] ? t0[2*j] : t0[2*j+1];
        #pragma unroll
        for (int j = 0; j < 4;  ++j) t2[j] = t1[2*j] > t1[2*j+1] ? t1[2*j] : t1[2*j+1];
        #pragma unroll
        for (int j = 0; j < 2;  ++j) t3[j] = t2[2*j] > t2[2*j+1] ? t2[2*j] : t2[2*j+1];
        const uint32_t mloc = t3[0] > t3[1] ? t3[0] : t3[1];

        uint32_t g = mloc;
        #pragma unroll
        for (int off = 1; off <= 32; off <<= 1) {
            uint32_t og = __shfl_xor(g, off);
            g = og > g ? og : g;
        }
        unsigned long long bal = __ballot(mloc == g);
        int owner = __ffsll(bal) - 1;
        int bj = 0;
        #pragma unroll
        for (int j = 31; j >= 0; --j)
            if (a[j] == g) bj = j;
        int bjo = __shfl(bj, owner);
        uint32_t gidx = (uint32_t)owner * 32u + (uint32_t)bjo;
        if (lane == it) wi = gidx;
        if (lane == owner) {
            #pragma unroll
            for (int j = 0; j < 32; ++j)
                if (j == bjo) a[j] = 0u;
        }
    }

    int rank = 0;
    #pragma unroll
    for (int m = 0; m < 32; ++m) {
        uint32_t om = __shfl(wi, m);
        rank += (om < wi) ? 1 : 0;
    }
    if (lane < KSP) {
        int idx = (int)wi;
        zidx[(size_t)row * KSP + rank] = idx;
        zval[(size_t)row * KSP + rank] = ur[idx];
    }
}

// ---------------------------------------------------------------------------
__global__ __launch_bounds__(256) void zfill_scatter_kernel(const int* __restrict__ zidx,
                                                            const float* __restrict__ zval,
                                                            float* __restrict__ zden)
{
    const int t  = threadIdx.x;
    const int r0 = blockIdx.x * 8;
    float* base = zden + (size_t)r0 * CODE_DIM;
    const float4 zero = make_float4(0.f, 0.f, 0.f, 0.f);
    for (int q = t; q < 8 * CODE_DIM / 4; q += 256)
        *(float4*)&base[q * 4] = zero;
    __syncthreads();
    const int rl = t >> 5, k = t & 31;
    int   idx = zidx[(size_t)(r0 + rl) * KSP + k];
    float v   = zval[(size_t)(r0 + rl) * KSP + k];
    base[(size_t)rl * CODE_DIM + idx] = v;
}

// ---------------------------------------------------------------------------
__global__ __launch_bounds__(128) void recon_kernel(const int* __restrict__ zidx,
                                                    const float* __restrict__ zval,
                                                    const float* __restrict__ Dt,
                                                    float* __restrict__ recon)
{
    const int t   = threadIdx.x;
    const int row = blockIdx.x;
    float4 acc = make_float4(0.f, 0.f, 0.f, 0.f);
    const int*   ip = zidx + (size_t)row * KSP;
    const float* vp = zval + (size_t)row * KSP;
    for (int k = 0; k < KSP; ++k) {
        int   j = ip[k];
        float v = vp[k];
        float4 d = *(const float4*)&Dt[(size_t)j * INPUT_DIM + t * 4];
        acc.x = fmaf(v, d.x, acc.x);
        acc.y = fmaf(v, d.y, acc.y);
        acc.z = fmaf(v, d.z, acc.z);
        acc.w = fmaf(v, d.w, acc.w);
    }
    *(float4*)&recon[(size_t)row * INPUT_DIM + t * 4] = acc;
}

// ---------------------------------------------------------------------------
extern "C" void kernel_launch(void* const* d_in, const int* in_sizes, int n_in,
                              void* d_out, int out_size, void* d_ws, size_t ws_size,
                              hipStream_t stream)
{
    const float* x = (const float*)d_in[0];
    const float* W = (const float*)d_in[1];   // [5][512][2048]
    const float* S = (const float*)d_in[2];   // [5][2048][2048]
    const float* D = (const float*)d_in[3];   // [512][2048]

    float* recon = (float*)d_out;
    float* zden  = (float*)d_out + (size_t)BATCH * INPUT_DIM;  // u scratch, then dense z
    unsigned short* ub = (unsigned short*)zden;                // bf16 u (fast path)

    char* p = (char*)d_ws;
    int*            zidx = (int*)p;            p += (size_t)BATCH * KSP * 4;
    float*          zval = (float*)p;          p += (size_t)BATCH * KSP * 4;
    float*          Dt   = (float*)p;          p += (size_t)CODE_DIM * INPUT_DIM * 4;
    int*            cidx = (int*)p;            p += (size_t)BATCH * NCAND * 4;
    float*          WT   = (float*)p;          p += (size_t)CODE_DIM * INPUT_DIM * 4;
    unsigned short* WbT  = (unsigned short*)p; p += (size_t)CODE_DIM * INPUT_DIM * 2;
    unsigned short* xb   = (unsigned short*)p; p += (size_t)BATCH * INPUT_DIM * 2;
    float*          zaC  = (float*)p;          p += (size_t)8192 * CODE_DIM * 4;     // 67 MB
    const size_t need = (size_t)(p - (char*)d_ws);
    const bool fast = ws_size >= need;

    // za regions: A = zden second half (16384 rows), B = recon (8192), C = ws (8192)
    float* zaA = (float*)((char*)zden + (size_t)BATCH * CODE_DIM * 2);  // after bf16 u
    float* zaB = recon;

    transpose_512x2048_kernel<<<dim3(CODE_DIM / 32, INPUT_DIM / 32), dim3(32, 8), 0, stream>>>(D, Dt);

    if (fast) {
        cvt_x_kernel<<<BATCH * INPUT_DIM / (256 * 8), 256, 0, stream>>>(x, xb);
        for (int l = 0; l < LAYERS; ++l) {
            const float* Wl = W + (size_t)l * INPUT_DIM * CODE_DIM;
            const float* Sl = (l == 0) ? nullptr : S + (size_t)l * CODE_DIM * CODE_DIM;
            wt_dual_kernel<<<dim3(CODE_DIM / 32, INPUT_DIM / 32), dim3(32, 8), 0, stream>>>(Wl, WT, WbT);
            screen_kernel<<<dim3(CODE_DIM / 128, BATCH / 128), 256, 0, stream>>>(xb, WbT, ub);
            if (l > 0)
                za_add_kernel<<<dim3(BATCH / 128, CODE_DIM / 256), 256, 0, stream>>>(
                    Sl, zidx, zval, zaA, zaB, zaC);
            topk40_kernel<<<BATCH / 4, 256, 0, stream>>>(
                ub, zaA, zaB, zaC, cidx, l > 0 ? 1 : 0);
            refine_za_kernel<<<BATCH / 4, 256, 0, stream>>>(
                x, WT, zaA, zaB, zaC, cidx, zidx, zval, l > 0 ? 1 : 0);
        }
    } else {
        for (int l = 0; l < LAYERS; ++l) {
            const float* Wl = W + (size_t)l * INPUT_DIM * CODE_DIM;
            const float* Sl = (l == 0) ? nullptr : S + (size_t)l * CODE_DIM * CODE_DIM;
            gemm_layer_kernel<<<dim3(CODE_DIM / 128, BATCH / 128), 256, 0, stream>>>(
                x, Wl, Sl, (l == 0) ? nullptr : zidx, (l == 0) ? nullptr : zval, zden);
            topk32_wave_kernel<<<BATCH / 4, 256, 0, stream>>>(zden, zidx, zval);
        }
    }

    zfill_scatter_kernel<<<BATCH / 8, 256, 0, stream>>>(zidx, zval, zden);
    recon_kernel<<<BATCH, 128, 0, stream>>>(zidx, zval, Dt, recon);
}

// Round 27
// 5122.432 us; speedup vs baseline: 1.1223x; 1.0242x over previous
//
#include <hip/hip_runtime.h>
#include <stdint.h>

#define LAYERS    5
#define INPUT_DIM 512
#define CODE_DIM  2048
#define BATCH     32768
#define KSP       32
#define NCAND     40

typedef __attribute__((ext_vector_type(8))) short bf16x8;
typedef __attribute__((ext_vector_type(4))) float f32x4;

__device__ __forceinline__ unsigned short f2bf(float f) {
    uint32_t u = __float_as_uint(f);
    uint32_t r = (u + 0x7fffu + ((u >> 16) & 1u)) >> 16;   // RNE
    return (unsigned short)r;
}

// za region select: rows [0,16384) -> zaA, [16384,24576) -> zaB, rest -> zaC
__device__ __forceinline__ float* za_row(float* zaA, float* zaB, float* zaC, int row) {
    return (row < 16384) ? zaA + (size_t)row * CODE_DIM
         : (row < 24576) ? zaB + (size_t)(row - 16384) * CODE_DIM
                         : zaC + (size_t)(row - 24576) * CODE_DIM;
}

#define GLOAD_LDS16(dst, src) \
    __builtin_amdgcn_global_load_lds((const __attribute__((address_space(1))) uint32_t*)(src), \
                                     (__attribute__((address_space(3))) uint32_t*)(dst), 16, 0, 0)

// ---------------------------------------------------------------------------
// src [512][2048] f32 -> dst [2048][512] f32  (bit copy; used for Dt)
__global__ __launch_bounds__(256) void transpose_512x2048_kernel(const float* __restrict__ src,
                                                                 float* __restrict__ dst)
{
    __shared__ float tile[32][33];
    const int tx = threadIdx.x;
    const int ty = threadIdx.y;
    const int cb = blockIdx.x * 32;
    const int ib = blockIdx.y * 32;
    #pragma unroll
    for (int j = 0; j < 32; j += 8)
        tile[ty + j][tx] = src[(size_t)(ib + ty + j) * CODE_DIM + cb + tx];
    __syncthreads();
    #pragma unroll
    for (int j = 0; j < 32; j += 8)
        dst[(size_t)(cb + ty + j) * INPUT_DIM + ib + tx] = tile[tx][ty + j];
}

// ---------------------------------------------------------------------------
// W [512][2048] f32 -> WT [2048][512] f32 AND WbT [2048][512] bf16 (one pass)
__global__ __launch_bounds__(256) void wt_dual_kernel(const float* __restrict__ src,
                                                      float* __restrict__ wt,
                                                      unsigned short* __restrict__ wbt)
{
    __shared__ float tile[32][33];
    const int tx = threadIdx.x;
    const int ty = threadIdx.y;
    const int cb = blockIdx.x * 32;
    const int ib = blockIdx.y * 32;
    #pragma unroll
    for (int j = 0; j < 32; j += 8)
        tile[ty + j][tx] = src[(size_t)(ib + ty + j) * CODE_DIM + cb + tx];
    __syncthreads();
    #pragma unroll
    for (int j = 0; j < 32; j += 8) {
        float v = tile[tx][ty + j];
        wt [(size_t)(cb + ty + j) * INPUT_DIM + ib + tx] = v;
        wbt[(size_t)(cb + ty + j) * INPUT_DIM + ib + tx] = f2bf(v);
    }
}

// ---------------------------------------------------------------------------
// x f32 [32768*512] -> xb bf16 (8 elems/thread)
__global__ __launch_bounds__(256) void cvt_x_kernel(const float* __restrict__ s,
                                                    unsigned short* __restrict__ d)
{
    const size_t base = ((size_t)blockIdx.x * 256 + threadIdx.x) * 8;
    float4 a = *(const float4*)&s[base];
    float4 b = *(const float4*)&s[base + 4];
    uint4 o;
    o.x = (uint32_t)f2bf(a.x) | ((uint32_t)f2bf(a.y) << 16);
    o.y = (uint32_t)f2bf(a.z) | ((uint32_t)f2bf(a.w) << 16);
    o.z = (uint32_t)f2bf(b.x) | ((uint32_t)f2bf(b.y) << 16);
    o.w = (uint32_t)f2bf(b.z) | ((uint32_t)f2bf(b.w) << 16);
    *(uint4*)&d[base] = o;
}

// ---------------------------------------------------------------------------
// SCREEN (pure bf16 MFMA xW).  Double-buffered gload-only LDS staging.
// Fragment maps validated r17.
__global__ __launch_bounds__(256) void screen_kernel(
    const unsigned short* __restrict__ xb, const unsigned short* __restrict__ WbT,
    unsigned short* __restrict__ u)
{
    __shared__ unsigned short Ash[2][128][32];   // 16 KB, gload dest (linear)
    __shared__ unsigned short Bsh[2][128][32];   // 16 KB

    const int t    = threadIdx.x;
    const int lane = t & 63;
    const int w    = t >> 6;
    const int m16  = lane & 15;
    const int g    = lane >> 4;
    const int c0   = blockIdx.x * 128;
    const int r0   = blockIdx.y * 128;

    const int srow  = lane >> 2;              // 0..15
    const int spart = (lane & 3) * 8;         // short offset within row

#define GLOAD_T(B, KT)                                                        \
    GLOAD_LDS16(&Ash[B][w * 32][0],                                           \
        xb  + (size_t)(r0 + w * 32 + srow) * INPUT_DIM + (KT) + spart);       \
    GLOAD_LDS16(&Ash[B][w * 32 + 16][0],                                      \
        xb  + (size_t)(r0 + w * 32 + 16 + srow) * INPUT_DIM + (KT) + spart);  \
    GLOAD_LDS16(&Bsh[B][w * 32][0],                                           \
        WbT + (size_t)(c0 + w * 32 + srow) * INPUT_DIM + (KT) + spart);       \
    GLOAD_LDS16(&Bsh[B][w * 32 + 16][0],                                      \
        WbT + (size_t)(c0 + w * 32 + 16 + srow) * INPUT_DIM + (KT) + spart);

#define COMPUTE_T(B)                                                          \
    {                                                                         \
        bf16x8 af0 = *(const bf16x8*)&Ash[B][w * 32 + m16][g * 8];            \
        bf16x8 af1 = *(const bf16x8*)&Ash[B][w * 32 + 16 + m16][g * 8];       \
        _Pragma("unroll")                                                     \
        for (int ns = 0; ns < 8; ++ns) {                                      \
            bf16x8 bfv = *(const bf16x8*)&Bsh[B][ns * 16 + m16][g * 8];       \
            acc[0][ns] = __builtin_amdgcn_mfma_f32_16x16x32_bf16(af0, bfv, acc[0][ns], 0, 0, 0); \
            acc[1][ns] = __builtin_amdgcn_mfma_f32_16x16x32_bf16(af1, bfv, acc[1][ns], 0, 0, 0); \
        }                                                                     \
    }

    f32x4 acc[2][8];
    #pragma unroll
    for (int mr = 0; mr < 2; ++mr)
        #pragma unroll
        for (int ns = 0; ns < 8; ++ns) acc[mr][ns] = (f32x4){0.f, 0.f, 0.f, 0.f};

    GLOAD_T(0, 0);
    __syncthreads();

    for (int kt = 0; kt < INPUT_DIM; kt += 64) {
        GLOAD_T(1, kt + 32);
        COMPUTE_T(0);
        __syncthreads();
        if (kt + 64 < INPUT_DIM) {
            GLOAD_T(0, kt + 64);
        }
        COMPUTE_T(1);
        __syncthreads();
    }

#undef GLOAD_T
#undef COMPUTE_T

    #pragma unroll
    for (int mr = 0; mr < 2; ++mr)
        #pragma unroll
        for (int ns = 0; ns < 8; ++ns)
            #pragma unroll
            for (int q = 0; q < 4; ++q) {
                const int row = r0 + w * 32 + mr * 16 + g * 4 + q;
                u[(size_t)row * CODE_DIM + c0 + ns * 16 + m16] = f2bf(acc[mr][ns][q]);
            }
}

// ---------------------------------------------------------------------------
// ZA_ADD: block-parallel exact za (contract chain: zero-init, ascending-index
// fold, f32 fmaf) for 128 rows x 256 cols per block.  Dense za only.
// Grid: blockIdx.x = row group (fast), blockIdx.y = column panel (slow) ->
// 2 MB S-panel L2-resident across concurrent row-blocks.
__global__ __launch_bounds__(256) void za_add_kernel(
    const float* __restrict__ Sl, const int* __restrict__ zidx,
    const float* __restrict__ zval, float* zaA, float* zaB, float* zaC)
{
    __shared__ int   pidx[128][KSP];   // 16 KB
    __shared__ float pval[128][KSP];   // 16 KB

    const int t  = threadIdx.x;
    const int r0 = blockIdx.x * 128;   // row group (fast dim)
    const int c0 = blockIdx.y * 256;   // column panel (slow dim -> L2 reuse)

    for (int i = t; i < 128 * KSP; i += 256) {
        int r = i >> 5, k = i & 31;
        pidx[r][k] = zidx[(size_t)(r0 + r) * KSP + k];
        pval[r][k] = zval[(size_t)(r0 + r) * KSP + k];
    }
    __syncthreads();

    const int rg = t >> 6;            // 0..3 -> rows rg*32 .. rg*32+31
    const int cq = (t & 63) * 4;      // 4 consecutive cols

    for (int rr = 0; rr < 32; ++rr) {
        const int r = rg * 32 + rr;
        float4 za = make_float4(0.f, 0.f, 0.f, 0.f);
        for (int k = 0; k < KSP; ++k) {           // ascending-index fold
            int   j = pidx[r][k];
            float v = pval[r][k];
            float4 s = *(const float4*)&Sl[(size_t)j * CODE_DIM + c0 + cq];
            za.x = fmaf(v, s.x, za.x);
            za.y = fmaf(v, s.y, za.y);
            za.z = fmaf(v, s.z, za.z);
            za.w = fmaf(v, s.w, za.w);
        }
        float* zap = za_row(zaA, zaB, zaC, r0 + r);
        *(float4*)&zap[c0 + cq] = za;             // exact za
    }
}

// ---------------------------------------------------------------------------
// FUSED TOPK40 + REFINE: one wave per row.
//  Phase 1 (r23-validated key math): keys f32 = |dequant(bf16 xw) + za|;
//    za row values dumped TRANSPOSED to per-wave LDS (zs[w][j*64+lane],
//    conflict-free) so phase 3 needs no HBM za gather.
//  Phase 2 (r12-validated selection): key tree + ballot owner-select;
//    lane it holds winner index wi of slot it.
//  Phase 3 (r23-validated refine chain): lanes 0..39 recompute the exact
//    np-faithful xW chain (k=0..511 ascending f32 fmaf; x read broadcast
//    from global) + single add of the exact za from LDS -> bitwise-identical
//    z values; exact top-32 select; index-sorted write.
__global__ __launch_bounds__(256) void topk_refine_kernel(
    const unsigned short* __restrict__ u, const float* __restrict__ x,
    const float* __restrict__ WT, float* zaA, float* zaB, float* zaC,
    int* __restrict__ zidx, float* __restrict__ zval, int has_sparse)
{
    __shared__ float zs[4][CODE_DIM];   // 32 KB; per-wave region, no barrier

    const int lane = threadIdx.x & 63;
    const int w    = threadIdx.x >> 6;
    const int row  = blockIdx.x * 4 + w;
    const unsigned short* ur = u + (size_t)row * CODE_DIM + lane * 32;

    // ---- phase 1: za load + LDS dump + keys ----
    float zal[32];
    if (has_sparse) {
        const float* zap = za_row(zaA, zaB, zaC, row) + lane * 32;
        #pragma unroll
        for (int q = 0; q < 8; ++q) {
            float4 zv = *(const float4*)&zap[q * 4];
            zal[q * 4 + 0] = zv.x;
            zal[q * 4 + 1] = zv.y;
            zal[q * 4 + 2] = zv.z;
            zal[q * 4 + 3] = zv.w;
        }
        #pragma unroll
        for (int j = 0; j < 32; ++j)          // transposed: bank = lane%32, free
            zs[w][j * 64 + lane] = zal[j];
    } else {
        #pragma unroll
        for (int i = 0; i < 32; ++i) zal[i] = 0.f;
    }

    uint32_t a[32];
    {
        float f;
#define KEY2(word, base)                                                      \
        f = __uint_as_float((uint32_t)(word) << 16) + zal[base];              \
        a[base] = (__float_as_uint(f) & 0x7fffffffu) + 1u;                    \
        f = __uint_as_float((uint32_t)(word) & 0xffff0000u) + zal[(base) + 1];\
        a[(base) + 1] = (__float_as_uint(f) & 0x7fffffffu) + 1u;
        #pragma unroll
        for (int q = 0; q < 4; ++q) {
            uint4 v = *(const uint4*)&ur[q * 8];
            KEY2(v.x, q * 8 + 0)
            KEY2(v.y, q * 8 + 2)
            KEY2(v.z, q * 8 + 4)
            KEY2(v.w, q * 8 + 6)
        }
#undef KEY2
    }

    // ---- phase 2: top-NCAND selection ----
    uint32_t wi = 0xFFFFFFFFu;
    for (int it = 0; it < NCAND; ++it) {
        uint32_t t0[16], t1[8], t2[4], t3[2];
        #pragma unroll
        for (int j = 0; j < 16; ++j) t0[j] = a[2*j]  > a[2*j+1]  ? a[2*j]  : a[2*j+1];
        #pragma unroll
        for (int j = 0; j < 8;  ++j) t1[j] = t0[2*j] > t0[2*j+1] ? t0[2*j] : t0[2*j+1];
        #pragma unroll
        for (int j = 0; j < 4;  ++j) t2[j] = t1[2*j] > t1[2*j+1] ? t1[2*j] : t1[2*j+1];
        #pragma unroll
        for (int j = 0; j < 2;  ++j) t3[j] = t2[2*j] > t2[2*j+1] ? t2[2*j] : t2[2*j+1];
        const uint32_t mloc = t3[0] > t3[1] ? t3[0] : t3[1];

        uint32_t gmax = mloc;
        #pragma unroll
        for (int off = 1; off <= 32; off <<= 1) {
            uint32_t og = __shfl_xor(gmax, off);
            gmax = og > gmax ? og : gmax;
        }

        unsigned long long bal = __ballot(mloc == gmax);
        int owner = __ffsll(bal) - 1;

        int bj = 0;
        #pragma unroll
        for (int j = 31; j >= 0; --j)
            if (a[j] == gmax) bj = j;
        int bjo = __shfl(bj, owner);

        uint32_t gidx = (uint32_t)owner * 32u + (uint32_t)bjo;
        if (lane == it) wi = gidx;

        if (lane == owner) {
            #pragma unroll
            for (int j = 0; j < 32; ++j)
                if (j == bjo) a[j] = 0u;
        }
    }

    // ---- phase 3: exact refine of the NCAND candidates ----
    int   c  = 0x7fffffff;
    float ra = 0.f;
    if (lane < NCAND) {
        c = (int)wi;
        const float* wc = WT + (size_t)c * INPUT_DIM;
        const float* xr = x + (size_t)row * INPUT_DIM;
        #pragma unroll 8
        for (int kq = 0; kq < INPUT_DIM / 4; ++kq) {       // k strictly ascending
            float4 wv = *(const float4*)&wc[kq * 4];
            float4 xv = *(const float4*)&xr[kq * 4];       // broadcast read
            ra = fmaf(xv.x, wv.x, ra);
            ra = fmaf(xv.y, wv.y, ra);
            ra = fmaf(xv.z, wv.z, ra);
            ra = fmaf(xv.w, wv.w, ra);
        }
        if (has_sparse)
            ra = ra + zs[w][(c & 31) * 64 + (c >> 5)];     // single add: u = xw + zs
    }

    uint32_t key = (lane < NCAND) ? ((__float_as_uint(ra) & 0x7fffffffu) + 1u) : 0u;

    uint32_t si = 0u;
    for (int it = 0; it < KSP; ++it) {
        uint32_t bk = key;
        uint32_t bc = (key != 0u) ? (uint32_t)c : 0x7fffffffu;
        #pragma unroll
        for (int off = 1; off <= 32; off <<= 1) {
            uint32_t ok = (uint32_t)__shfl_xor((int)bk, off);
            uint32_t oc = (uint32_t)__shfl_xor((int)bc, off);
            if (ok > bk || (ok == bk && oc < bc)) { bk = ok; bc = oc; }
        }
        if (lane == it) si = bc;
        if (key != 0u && (uint32_t)c == bc) key = 0u;
    }

    float va = 0.f;
    #pragma unroll
    for (int m = 0; m < NCAND; ++m) {
        uint32_t cm = (uint32_t)__shfl(c, m);
        float    am = __shfl(ra, m);
        if (lane < KSP && si == cm) va = am;
    }

    int rank = 0;
    #pragma unroll
    for (int m = 0; m < KSP; ++m) {
        uint32_t om = (uint32_t)__shfl((int)si, m);
        rank += (om < si) ? 1 : 0;
    }
    if (lane < KSP) {
        zidx[(size_t)row * KSP + rank] = (int)si;
        zval[(size_t)row * KSP + rank] = va;
    }
}

// ---------------------------------------------------------------------------
// FALLBACK (ws too small): r16 f32 gemm (84 VGPR, spill-free)
__global__ __launch_bounds__(256) void gemm_layer_kernel(
    const float* __restrict__ x, const float* __restrict__ Wl,
    const float* __restrict__ Sl, const int* __restrict__ zidx,
    const float* __restrict__ zval, float* __restrict__ u)
{
    __shared__ float As[32][128 + 4];

    const int t   = threadIdx.x;
    const int c0  = blockIdx.x * 128;
    const int r0  = blockIdx.y * 128;
    const int tm0 = (t >> 4) * 8;
    const int cn  = (t & 15) * 4;

    float acc[8][8];
    #pragma unroll
    for (int i = 0; i < 8; ++i)
        #pragma unroll
        for (int j = 0; j < 8; ++j) acc[i][j] = 0.f;

    for (int kt = 0; kt < INPUT_DIM; kt += 32) {
        #pragma unroll
        for (int i = 0; i < 4; ++i) {
            int f   = t * 4 + i;
            int row = f >> 3, kq = f & 7;
            float4 v = *(const float4*)&x[(size_t)(r0 + row) * INPUT_DIM + kt + kq * 4];
            As[kq * 4 + 0][row] = v.x;
            As[kq * 4 + 1][row] = v.y;
            As[kq * 4 + 2][row] = v.z;
            As[kq * 4 + 3][row] = v.w;
        }
        __syncthreads();
        const float* Wb = Wl + (size_t)kt * CODE_DIM + c0 + cn;
        #pragma unroll 4
        for (int kk = 0; kk < 32; ++kk) {
            float av[8], bv[8];
            *(float4*)&av[0] = *(const float4*)&As[kk][tm0];
            *(float4*)&av[4] = *(const float4*)&As[kk][tm0 + 4];
            const float* brow = Wb + (size_t)kk * CODE_DIM;
            *(float4*)&bv[0] = *(const float4*)&brow[0];
            *(float4*)&bv[4] = *(const float4*)&brow[64];
            #pragma unroll
            for (int i = 0; i < 8; ++i)
                #pragma unroll
                for (int j = 0; j < 8; ++j)
                    acc[i][j] = fmaf(av[i], bv[j], acc[i][j]);
        }
        __syncthreads();
    }

    if (Sl != nullptr) {
        #pragma unroll
        for (int i = 0; i < 8; ++i) {
            const int r = r0 + tm0 + i;
            const int*   ip = zidx + (size_t)r * KSP;
            const float* vp = zval + (size_t)r * KSP;
            float zacc[8];
            #pragma unroll
            for (int j = 0; j < 8; ++j) zacc[j] = 0.f;
            for (int k = 0; k < KSP; ++k) {
                int   j = ip[k];
                float v = vp[k];
                const float* srow = Sl + (size_t)j * CODE_DIM + c0 + cn;
                float4 s0 = *(const float4*)&srow[0];
                float4 s1 = *(const float4*)&srow[64];
                zacc[0] = fmaf(v, s0.x, zacc[0]);
                zacc[1] = fmaf(v, s0.y, zacc[1]);
                zacc[2] = fmaf(v, s0.z, zacc[2]);
                zacc[3] = fmaf(v, s0.w, zacc[3]);
                zacc[4] = fmaf(v, s1.x, zacc[4]);
                zacc[5] = fmaf(v, s1.y, zacc[5]);
                zacc[6] = fmaf(v, s1.z, zacc[6]);
                zacc[7] = fmaf(v, s1.w, zacc[7]);
            }
            #pragma unroll
            for (int j = 0; j < 8; ++j)
                acc[i][j] = acc[i][j] + zacc[j];
        }
    }

    #pragma unroll
    for (int i = 0; i < 8; ++i) {
        float* up = u + (size_t)(r0 + tm0 + i) * CODE_DIM + c0 + cn;
        *(float4*)&up[0]  = make_float4(acc[i][0], acc[i][1], acc[i][2], acc[i][3]);
        *(float4*)&up[64] = make_float4(acc[i][4], acc[i][5], acc[i][6], acc[i][7]);
    }
}

// ---------------------------------------------------------------------------
// FALLBACK top-32 on f32 u (exact, index-sorted output) — r12 kernel
__global__ __launch_bounds__(256) void topk32_wave_kernel(const float* __restrict__ u,
                                                          int* __restrict__ zidx,
                                                          float* __restrict__ zval)
{
    const int lane = threadIdx.x & 63;
    const int row  = blockIdx.x * 4 + (threadIdx.x >> 6);
    const float* ur = u + (size_t)row * CODE_DIM;

    uint32_t a[32];
    #pragma unroll
    for (int q = 0; q < 8; ++q) {
        float4 v = *(const float4*)&ur[lane * 32 + q * 4];
        a[q * 4 + 0] = (__float_as_uint(v.x) & 0x7fffffffu) + 1u;
        a[q * 4 + 1] = (__float_as_uint(v.y) & 0x7fffffffu) + 1u;
        a[q * 4 + 2] = (__float_as_uint(v.z) & 0x7fffffffu) + 1u;
        a[q * 4 + 3] = (__float_as_uint(v.w) & 0x7fffffffu) + 1u;
    }

    uint32_t wi = 0xFFFFFFFFu;
    for (int it = 0; it < KSP; ++it) {
        uint32_t t0[16], t1[8], t2[4], t3[2];
        #pragma unroll
        for (int j = 0; j < 16; ++j) t0[j] = a[2*j]  > a[2*j+1]  ? a[2*j]  : a[2*j+1];
        #pragma unroll
        for (int j = 0; j < 8;  ++j) t1[j] = t0[2*j] > t0[2*j+1] ? t0[2*j] : t0[2*j+1];
        #pragma unroll
        for (int j = 0; j < 4;  ++j) t2[j] = t1[2*j] > t1[2*j+1] ? t1[2*j] : t1[2*j+1];
        #pragma unroll
        for (int j = 0; j < 2;  ++j) t3[j] = t2[2*j] > t2[2*j+1] ? t2[2*j] : t2[2*j+1];
        const uint32_t mloc = t3[0] > t3[1] ? t3[0] : t3[1];

        uint32_t g = mloc;
        #pragma unroll
        for (int off = 1; off <= 32; off <<= 1) {
            uint32_t og = __shfl_xor(g, off);
            g = og > g ? og : g;
        }
        unsigned long long bal = __ballot(mloc == g);
        int owner = __ffsll(bal) - 1;
        int bj = 0;
        #pragma unroll
        for (int j = 31; j >= 0; --j)
            if (a[j] == g) bj = j;
        int bjo = __shfl(bj, owner);
        uint32_t gidx = (uint32_t)owner * 32u + (uint32_t)bjo;
        if (lane == it) wi = gidx;
        if (lane == owner) {
            #pragma unroll
            for (int j = 0; j < 32; ++j)
                if (j == bjo) a[j] = 0u;
        }
    }

    int rank = 0;
    #pragma unroll
    for (int m = 0; m < 32; ++m) {
        uint32_t om = __shfl(wi, m);
        rank += (om < wi) ? 1 : 0;
    }
    if (lane < KSP) {
        int idx = (int)wi;
        zidx[(size_t)row * KSP + rank] = idx;
        zval[(size_t)row * KSP + rank] = ur[idx];
    }
}

// ---------------------------------------------------------------------------
__global__ __launch_bounds__(256) void zfill_scatter_kernel(const int* __restrict__ zidx,
                                                            const float* __restrict__ zval,
                                                            float* __restrict__ zden)
{
    const int t  = threadIdx.x;
    const int r0 = blockIdx.x * 8;
    float* base = zden + (size_t)r0 * CODE_DIM;
    const float4 zero = make_float4(0.f, 0.f, 0.f, 0.f);
    for (int q = t; q < 8 * CODE_DIM / 4; q += 256)
        *(float4*)&base[q * 4] = zero;
    __syncthreads();
    const int rl = t >> 5, k = t & 31;
    int   idx = zidx[(size_t)(r0 + rl) * KSP + k];
    float v   = zval[(size_t)(r0 + rl) * KSP + k];
    base[(size_t)rl * CODE_DIM + idx] = v;
}

// ---------------------------------------------------------------------------
__global__ __launch_bounds__(128) void recon_kernel(const int* __restrict__ zidx,
                                                    const float* __restrict__ zval,
                                                    const float* __restrict__ Dt,
                                                    float* __restrict__ recon)
{
    const int t   = threadIdx.x;
    const int row = blockIdx.x;
    float4 acc = make_float4(0.f, 0.f, 0.f, 0.f);
    const int*   ip = zidx + (size_t)row * KSP;
    const float* vp = zval + (size_t)row * KSP;
    for (int k = 0; k < KSP; ++k) {
        int   j = ip[k];
        float v = vp[k];
        float4 d = *(const float4*)&Dt[(size_t)j * INPUT_DIM + t * 4];
        acc.x = fmaf(v, d.x, acc.x);
        acc.y = fmaf(v, d.y, acc.y);
        acc.z = fmaf(v, d.z, acc.z);
        acc.w = fmaf(v, d.w, acc.w);
    }
    *(float4*)&recon[(size_t)row * INPUT_DIM + t * 4] = acc;
}

// ---------------------------------------------------------------------------
extern "C" void kernel_launch(void* const* d_in, const int* in_sizes, int n_in,
                              void* d_out, int out_size, void* d_ws, size_t ws_size,
                              hipStream_t stream)
{
    const float* x = (const float*)d_in[0];
    const float* W = (const float*)d_in[1];   // [5][512][2048]
    const float* S = (const float*)d_in[2];   // [5][2048][2048]
    const float* D = (const float*)d_in[3];   // [512][2048]

    float* recon = (float*)d_out;
    float* zden  = (float*)d_out + (size_t)BATCH * INPUT_DIM;  // u scratch, then dense z
    unsigned short* ub = (unsigned short*)zden;                // bf16 u (fast path)

    char* p = (char*)d_ws;
    int*            zidx = (int*)p;            p += (size_t)BATCH * KSP * 4;
    float*          zval = (float*)p;          p += (size_t)BATCH * KSP * 4;
    float*          Dt   = (float*)p;          p += (size_t)CODE_DIM * INPUT_DIM * 4;
    float*          WT   = (float*)p;          p += (size_t)CODE_DIM * INPUT_DIM * 4;
    unsigned short* WbT  = (unsigned short*)p; p += (size_t)CODE_DIM * INPUT_DIM * 2;
    unsigned short* xb   = (unsigned short*)p; p += (size_t)BATCH * INPUT_DIM * 2;
    float*          zaC  = (float*)p;          p += (size_t)8192 * CODE_DIM * 4;     // 67 MB
    const size_t need = (size_t)(p - (char*)d_ws);
    const bool fast = ws_size >= need;

    // za regions: A = zden second half (16384 rows), B = recon (8192), C = ws (8192)
    float* zaA = (float*)((char*)zden + (size_t)BATCH * CODE_DIM * 2);  // after bf16 u
    float* zaB = recon;

    transpose_512x2048_kernel<<<dim3(CODE_DIM / 32, INPUT_DIM / 32), dim3(32, 8), 0, stream>>>(D, Dt);

    if (fast) {
        cvt_x_kernel<<<BATCH * INPUT_DIM / (256 * 8), 256, 0, stream>>>(x, xb);
        for (int l = 0; l < LAYERS; ++l) {
            const float* Wl = W + (size_t)l * INPUT_DIM * CODE_DIM;
            const float* Sl = (l == 0) ? nullptr : S + (size_t)l * CODE_DIM * CODE_DIM;
            wt_dual_kernel<<<dim3(CODE_DIM / 32, INPUT_DIM / 32), dim3(32, 8), 0, stream>>>(Wl, WT, WbT);
            screen_kernel<<<dim3(CODE_DIM / 128, BATCH / 128), 256, 0, stream>>>(xb, WbT, ub);
            if (l > 0)
                za_add_kernel<<<dim3(BATCH / 128, CODE_DIM / 256), 256, 0, stream>>>(
                    Sl, zidx, zval, zaA, zaB, zaC);
            topk_refine_kernel<<<BATCH / 4, 256, 0, stream>>>(
                ub, x, WT, zaA, zaB, zaC, zidx, zval, l > 0 ? 1 : 0);
        }
    } else {
        for (int l = 0; l < LAYERS; ++l) {
            const float* Wl = W + (size_t)l * INPUT_DIM * CODE_DIM;
            const float* Sl = (l == 0) ? nullptr : S + (size_t)l * CODE_DIM * CODE_DIM;
            gemm_layer_kernel<<<dim3(CODE_DIM / 128, BATCH / 128), 256, 0, stream>>>(
                x, Wl, Sl, (l == 0) ? nullptr : zidx, (l == 0) ? nullptr : zval, zden);
            topk32_wave_kernel<<<BATCH / 4, 256, 0, stream>>>(zden, zidx, zval);
        }
    }

    zfill_scatter_kernel<<<BATCH / 8, 256, 0, stream>>>(zidx, zval, zden);
    recon_kernel<<<BATCH, 128, 0, stream>>>(zidx, zval, Dt, recon);
}